// Round 1
// baseline (621.895 us; speedup 1.0000x reference)
//
#include <hip/hip_runtime.h>

// GCN forward: 2× (GEMM + symmetric-normalized aggregation), fp32.
// CSR built on the fly (count -> scan -> fill), atomic-free aggregation.

#define F_IN  128
#define F_H   128
#define F_OUT 40

// ---------------- CSR build ----------------

__global__ void k_init(int* __restrict__ deg, int* __restrict__ cnt2, int n) {
    int i = blockIdx.x * 256 + threadIdx.x;
    if (i < n) { deg[i] = 0; cnt2[i] = 0; }
}

__global__ void k_count(const int* __restrict__ dst, int* __restrict__ deg, int e) {
    int i = blockIdx.x * 256 + threadIdx.x;
    if (i < e) atomicAdd(&deg[dst[i]], 1);
}

__global__ void k_dinv(const int* __restrict__ deg, float* __restrict__ dinv, int n) {
    int i = blockIdx.x * 256 + threadIdx.x;
    if (i < n) dinv[i] = rsqrtf((float)deg[i] + 1.0f);   // +1 self-loop
}

// block-level exclusive scan (1024 elems/block) + block sums
__global__ void k_scan1(const int* __restrict__ cnt, int* __restrict__ out,
                        int* __restrict__ bsum, int n) {
    __shared__ int s[1024];
    int i = blockIdx.x * 1024 + threadIdx.x;
    int v = (i < n) ? cnt[i] : 0;
    s[threadIdx.x] = v;
    __syncthreads();
    for (int off = 1; off < 1024; off <<= 1) {
        int t = (threadIdx.x >= off) ? s[threadIdx.x - off] : 0;
        __syncthreads();
        s[threadIdx.x] += t;
        __syncthreads();
    }
    if (i < n) out[i] = s[threadIdx.x] - v;
    if (threadIdx.x == 1023) bsum[blockIdx.x] = s[1023];
}

// scan the (<=128) block sums; bexcl[nb] = grand total
__global__ void k_scan2(const int* __restrict__ bsum, int* __restrict__ bexcl, int nb) {
    __shared__ int s[128];
    int v = (threadIdx.x < nb) ? bsum[threadIdx.x] : 0;
    s[threadIdx.x] = v;
    __syncthreads();
    for (int off = 1; off < 128; off <<= 1) {
        int t = (threadIdx.x >= off) ? s[threadIdx.x - off] : 0;
        __syncthreads();
        s[threadIdx.x] += t;
        __syncthreads();
    }
    if (threadIdx.x < nb) bexcl[threadIdx.x] = s[threadIdx.x] - v;
    if (threadIdx.x == 127) bexcl[nb] = s[127];
}

__global__ void k_scan3(int* __restrict__ out, const int* __restrict__ bexcl, int n, int nb) {
    int i = blockIdx.x * 256 + threadIdx.x;
    if (i < n) out[i] += bexcl[i >> 10];
    if (i == 0) out[n] = bexcl[nb];
}

__global__ void k_fill(const int* __restrict__ src, const int* __restrict__ dst,
                       const int* __restrict__ row_ptr, int* __restrict__ cnt2,
                       int* __restrict__ col, int e) {
    int i = blockIdx.x * 256 + threadIdx.x;
    if (i < e) {
        int d = dst[i];
        int pos = row_ptr[d] + atomicAdd(&cnt2[d], 1);
        col[pos] = src[i];
    }
}

// ---------------- GEMM 1: h1 = x @ W1  (N x 128 @ 128 x 128) ----------------

__global__ __launch_bounds__(256) void k_gemm1(const float* __restrict__ x,
                                               const float* __restrict__ W,
                                               float* __restrict__ h, int n) {
    __shared__ float xs[128][129];   // +1 pad: a-reads land on banks 8 apart
    __shared__ float wsh[128][128];
    const int tid = threadIdx.x;
    const int bm = blockIdx.x * 128;

    for (int i = tid * 4; i < 128 * 128; i += 256 * 4)
        *(float4*)&wsh[i >> 7][i & 127] = *(const float4*)&W[i];

    for (int i = tid * 4; i < 128 * 128; i += 256 * 4) {
        int r = i >> 7, c = i & 127;
        int gr = bm + r;
        float4 v = (gr < n) ? *(const float4*)&x[(size_t)gr * F_IN + c]
                            : make_float4(0.f, 0.f, 0.f, 0.f);
        xs[r][c] = v.x; xs[r][c + 1] = v.y; xs[r][c + 2] = v.z; xs[r][c + 3] = v.w;
    }
    __syncthreads();

    const int tc = (tid & 15) * 8;
    const int tr = (tid >> 4) * 8;
    float acc[8][8] = {};
    for (int k = 0; k < 128; ++k) {
        float a[8], b[8];
#pragma unroll
        for (int i = 0; i < 8; ++i) a[i] = xs[tr + i][k];
        *(float4*)&b[0] = *(const float4*)&wsh[k][tc];
        *(float4*)&b[4] = *(const float4*)&wsh[k][tc + 4];
#pragma unroll
        for (int i = 0; i < 8; ++i)
#pragma unroll
            for (int j = 0; j < 8; ++j)
                acc[i][j] = fmaf(a[i], b[j], acc[i][j]);
    }
#pragma unroll
    for (int i = 0; i < 8; ++i) {
        int gr = bm + tr + i;
        if (gr < n) {
            *(float4*)&h[(size_t)gr * F_H + tc]     = *(float4*)&acc[i][0];
            *(float4*)&h[(size_t)gr * F_H + tc + 4] = *(float4*)&acc[i][4];
        }
    }
}

// ---------------- Aggregation layer 1 (128 feats): wave per node ----------------

__global__ __launch_bounds__(256) void k_agg1(const float* __restrict__ h1,
                                              const int* __restrict__ row_ptr,
                                              const int* __restrict__ col,
                                              const float* __restrict__ dinv,
                                              const float* __restrict__ b1,
                                              float* __restrict__ out1, int n) {
    int wid = (blockIdx.x * 256 + threadIdx.x) >> 6;   // wave id = node
    int lane = threadIdx.x & 63;
    if (wid >= n) return;
    float di = dinv[wid];
    int beg = row_ptr[wid], end = row_ptr[wid + 1];
    float ax = 0.f, ay = 0.f;
    int c2 = lane * 2;
    for (int idx = beg; idx < end; ++idx) {
        int s = col[idx];
        float nrm = di * dinv[s];
        float2 v = *(const float2*)&h1[s * F_H + c2];
        ax = fmaf(v.x, nrm, ax);
        ay = fmaf(v.y, nrm, ay);
    }
    float2 hv = *(const float2*)&h1[wid * F_H + c2];
    float sn = di * di;
    ax = fmaf(hv.x, sn, ax) + b1[c2];
    ay = fmaf(hv.y, sn, ay) + b1[c2 + 1];
    float2 o;
    o.x = fmaxf(ax, 0.f);
    o.y = fmaxf(ay, 0.f);
    *(float2*)&out1[wid * F_H + c2] = o;
}

// ---------------- GEMM 2: h2 = out1 @ W2  (N x 128 @ 128 x 40) ----------------

__global__ __launch_bounds__(256) void k_gemm2(const float* __restrict__ xin,
                                               const float* __restrict__ W,
                                               float* __restrict__ h, int n) {
    __shared__ float xs[64][129];
    __shared__ float wsh[128 * F_OUT];
    const int tid = threadIdx.x;
    const int bm = blockIdx.x * 64;

    for (int i = tid; i < 128 * F_OUT; i += 256) wsh[i] = W[i];
    for (int i = tid * 4; i < 64 * 128; i += 256 * 4) {
        int r = i >> 7, c = i & 127;
        int gr = bm + r;
        float4 v = (gr < n) ? *(const float4*)&xin[(size_t)gr * F_H + c]
                            : make_float4(0.f, 0.f, 0.f, 0.f);
        xs[r][c] = v.x; xs[r][c + 1] = v.y; xs[r][c + 2] = v.z; xs[r][c + 3] = v.w;
    }
    __syncthreads();

    const int cg = (tid & 7) * 5;    // 8 col-groups x 5 cols = 40
    const int rg = (tid >> 3) * 2;   // 32 row-groups x 2 rows = 64
    float acc[2][5] = {};
    for (int k = 0; k < 128; ++k) {
        float a0 = xs[rg][k], a1 = xs[rg + 1][k];
#pragma unroll
        for (int j = 0; j < 5; ++j) {
            float b = wsh[k * F_OUT + cg + j];
            acc[0][j] = fmaf(a0, b, acc[0][j]);
            acc[1][j] = fmaf(a1, b, acc[1][j]);
        }
    }
#pragma unroll
    for (int i = 0; i < 2; ++i) {
        int gr = bm + rg + i;
        if (gr < n) {
#pragma unroll
            for (int j = 0; j < 5; ++j) h[(size_t)gr * F_OUT + cg + j] = acc[i][j];
        }
    }
}

// ---------------- Aggregation layer 2 (40 feats): wave per node ----------------

__global__ __launch_bounds__(256) void k_agg2(const float* __restrict__ h2,
                                              const int* __restrict__ row_ptr,
                                              const int* __restrict__ col,
                                              const float* __restrict__ dinv,
                                              const float* __restrict__ b2,
                                              float* __restrict__ out, int n) {
    int wid = (blockIdx.x * 256 + threadIdx.x) >> 6;
    int lane = threadIdx.x & 63;
    if (wid >= n) return;
    float di = dinv[wid];
    int beg = row_ptr[wid], end = row_ptr[wid + 1];
    float acc = 0.f;
    bool act = (lane < F_OUT);
    for (int idx = beg; idx < end; ++idx) {
        int s = col[idx];
        float nrm = di * dinv[s];
        float v = act ? h2[s * F_OUT + lane] : 0.f;
        acc = fmaf(v, nrm, acc);
    }
    if (act) {
        float hv = h2[wid * F_OUT + lane];
        acc = fmaf(hv, di * di, acc) + b2[lane];
        out[wid * F_OUT + lane] = acc;
    }
}

// ---------------- launch ----------------

extern "C" void kernel_launch(void* const* d_in, const int* in_sizes, int n_in,
                              void* d_out, int out_size, void* d_ws, size_t ws_size,
                              hipStream_t stream) {
    const float* x  = (const float*)d_in[0];
    const int*   ei = (const int*)d_in[1];
    const float* W1 = (const float*)d_in[2];
    const float* b1 = (const float*)d_in[3];
    const float* W2 = (const float*)d_in[4];
    const float* b2 = (const float*)d_in[5];
    float* out = (float*)d_out;

    const int N = in_sizes[0] / F_IN;     // 100000
    const int E = in_sizes[1] / 2;        // 1600000
    const int* src = ei;
    const int* dst = ei + E;

    char* ws = (char*)d_ws;
    size_t off = 0;
    auto alloc = [&](size_t bytes) -> void* {
        off = (off + 255) & ~(size_t)255;
        void* p = ws + off;
        off += bytes;
        return p;
    };
    int*   deg     = (int*)  alloc((size_t)N * 4);
    int*   cnt2    = (int*)  alloc((size_t)N * 4);
    float* dinv    = (float*)alloc((size_t)N * 4);
    int*   row_ptr = (int*)  alloc((size_t)(N + 1) * 4);
    int*   bsum    = (int*)  alloc(129 * 4);
    int*   bexcl   = (int*)  alloc(129 * 4);
    int*   col     = (int*)  alloc((size_t)E * 4);
    float* h1      = (float*)alloc((size_t)N * F_H * 4);
    float* out1    = (float*)alloc((size_t)N * F_H * 4);
    float* h2      = h1;   // h1 dead after k_agg1 -> reuse for h2 (N*40 <= N*128)

    const int gN  = (N + 255) / 256;
    const int gE  = (E + 255) / 256;
    const int nb  = (N + 1023) / 1024;   // 98 <= 128

    k_init <<<gN, 256, 0, stream>>>(deg, cnt2, N);
    k_count<<<gE, 256, 0, stream>>>(dst, deg, E);
    k_dinv <<<gN, 256, 0, stream>>>(deg, dinv, N);
    k_scan1<<<nb, 1024, 0, stream>>>(deg, row_ptr, bsum, N);
    k_scan2<<<1, 128, 0, stream>>>(bsum, bexcl, nb);
    k_scan3<<<gN, 256, 0, stream>>>(row_ptr, bexcl, N, nb);
    k_fill <<<gE, 256, 0, stream>>>(src, dst, row_ptr, cnt2, col, E);

    k_gemm1<<<(N + 127) / 128, 256, 0, stream>>>(x, W1, h1, N);
    k_agg1 <<<(N + 3) / 4, 256, 0, stream>>>(h1, row_ptr, col, dinv, b1, out1, N);
    k_gemm2<<<(N + 63) / 64, 256, 0, stream>>>(out1, W2, h2, N);
    k_agg2 <<<(N + 3) / 4, 256, 0, stream>>>(h2, row_ptr, col, dinv, b2, out, N);
}

// Round 2
// 499.409 us; speedup vs baseline: 1.2453x; 1.2453x over previous
//
#include <hip/hip_runtime.h>

// GCN forward: 2x (GEMM + symmetric-normalized aggregation), fp32.
// CSR built per call (count -> scan -> fill).
// Key trick: GEMM epilogue pre-scales each row by dinv[row], so the
// aggregation inner loop is a pure gather-accumulate (no dependent dinv
// load, no per-edge multiply): out[i] = d_i * (sum_s h_s[s] + h_s[i]) + b.

#define F_IN  128
#define F_H   128
#define F_OUT 40

// ---------------- CSR build ----------------

__global__ void k_count(const int* __restrict__ dst, int* __restrict__ deg, int e) {
    int i = blockIdx.x * 256 + threadIdx.x;
    if (i < e) atomicAdd(&deg[dst[i]], 1);
}

__global__ void k_dinv(const int* __restrict__ deg, float* __restrict__ dinv, int n) {
    int i = blockIdx.x * 256 + threadIdx.x;
    if (i < n) dinv[i] = rsqrtf((float)deg[i] + 1.0f);   // +1 self-loop
}

// block-level exclusive scan (1024 elems/block) + block sums
__global__ void k_scan1(const int* __restrict__ cnt, int* __restrict__ out,
                        int* __restrict__ bsum, int n) {
    __shared__ int s[1024];
    int i = blockIdx.x * 1024 + threadIdx.x;
    int v = (i < n) ? cnt[i] : 0;
    s[threadIdx.x] = v;
    __syncthreads();
    for (int off = 1; off < 1024; off <<= 1) {
        int t = (threadIdx.x >= off) ? s[threadIdx.x - off] : 0;
        __syncthreads();
        s[threadIdx.x] += t;
        __syncthreads();
    }
    if (i < n) out[i] = s[threadIdx.x] - v;
    if (threadIdx.x == 1023) bsum[blockIdx.x] = s[1023];
}

__global__ void k_scan2(const int* __restrict__ bsum, int* __restrict__ bexcl, int nb) {
    __shared__ int s[128];
    int v = (threadIdx.x < nb) ? bsum[threadIdx.x] : 0;
    s[threadIdx.x] = v;
    __syncthreads();
    for (int off = 1; off < 128; off <<= 1) {
        int t = (threadIdx.x >= off) ? s[threadIdx.x - off] : 0;
        __syncthreads();
        s[threadIdx.x] += t;
        __syncthreads();
    }
    if (threadIdx.x < nb) bexcl[threadIdx.x] = s[threadIdx.x] - v;
    if (threadIdx.x == 127) bexcl[nb] = s[127];
}

__global__ void k_scan3(int* __restrict__ out, const int* __restrict__ bexcl, int n, int nb) {
    int i = blockIdx.x * 256 + threadIdx.x;
    if (i < n) out[i] += bexcl[i >> 10];
    if (i == 0) out[n] = bexcl[nb];
}

__global__ void k_fill(const int* __restrict__ src, const int* __restrict__ dst,
                       const int* __restrict__ row_ptr, int* __restrict__ cnt2,
                       int* __restrict__ col, int e) {
    int i = blockIdx.x * 256 + threadIdx.x;
    if (i < e) {
        int d = dst[i];
        int pos = row_ptr[d] + atomicAdd(&cnt2[d], 1);
        col[pos] = src[i];
    }
}

// ---------------- GEMM 1: h1s = dinv .* (x @ W1)  (N x 128 @ 128 x 128) --------

__global__ __launch_bounds__(256) void k_gemm1(const float* __restrict__ x,
                                               const float* __restrict__ W,
                                               const float* __restrict__ dinv,
                                               float* __restrict__ h, int n) {
    __shared__ float xs[128][129];
    __shared__ float wsh[128][128];
    const int tid = threadIdx.x;
    const int bm = blockIdx.x * 128;

    for (int i = tid * 4; i < 128 * 128; i += 256 * 4)
        *(float4*)&wsh[i >> 7][i & 127] = *(const float4*)&W[i];

    for (int i = tid * 4; i < 128 * 128; i += 256 * 4) {
        int r = i >> 7, c = i & 127;
        int gr = bm + r;
        float4 v = (gr < n) ? *(const float4*)&x[(size_t)gr * F_IN + c]
                            : make_float4(0.f, 0.f, 0.f, 0.f);
        xs[r][c] = v.x; xs[r][c + 1] = v.y; xs[r][c + 2] = v.z; xs[r][c + 3] = v.w;
    }
    __syncthreads();

    const int tc = (tid & 15) * 8;
    const int tr = (tid >> 4) * 8;
    float acc[8][8] = {};
    for (int k = 0; k < 128; ++k) {
        float a[8], b[8];
#pragma unroll
        for (int i = 0; i < 8; ++i) a[i] = xs[tr + i][k];
        *(float4*)&b[0] = *(const float4*)&wsh[k][tc];
        *(float4*)&b[4] = *(const float4*)&wsh[k][tc + 4];
#pragma unroll
        for (int i = 0; i < 8; ++i)
#pragma unroll
            for (int j = 0; j < 8; ++j)
                acc[i][j] = fmaf(a[i], b[j], acc[i][j]);
    }
#pragma unroll
    for (int i = 0; i < 8; ++i) {
        int gr = bm + tr + i;
        if (gr < n) {
            float d = dinv[gr];
#pragma unroll
            for (int j = 0; j < 8; ++j) acc[i][j] *= d;
            *(float4*)&h[(size_t)gr * F_H + tc]     = *(float4*)&acc[i][0];
            *(float4*)&h[(size_t)gr * F_H + tc + 4] = *(float4*)&acc[i][4];
        }
    }
}

// -------- Aggregation layer 1 (128 feats): wave/node, 8-deep gather pipeline ----

__global__ __launch_bounds__(256) void k_agg1(const float* __restrict__ h1s,
                                              const int* __restrict__ row_ptr,
                                              const int* __restrict__ col,
                                              const float* __restrict__ dinv,
                                              const float* __restrict__ b1,
                                              float* __restrict__ out1, int n) {
    int wid = (blockIdx.x * 256 + threadIdx.x) >> 6;   // wave id = node
    int lane = threadIdx.x & 63;
    if (wid >= n) return;
    int beg = row_ptr[wid], end = row_ptr[wid + 1];
    const int c2 = lane * 2;
    const float* hb = h1s + c2;

    float a0x = 0.f, a0y = 0.f, a1x = 0.f, a1y = 0.f;
    float a2x = 0.f, a2y = 0.f, a3x = 0.f, a3y = 0.f;
    int idx = beg;
    for (; idx + 8 <= end; idx += 8) {
        int s0 = col[idx],     s1 = col[idx + 1], s2 = col[idx + 2], s3 = col[idx + 3];
        int s4 = col[idx + 4], s5 = col[idx + 5], s6 = col[idx + 6], s7 = col[idx + 7];
        float2 v0 = *(const float2*)(hb + (s0 << 7));
        float2 v1 = *(const float2*)(hb + (s1 << 7));
        float2 v2 = *(const float2*)(hb + (s2 << 7));
        float2 v3 = *(const float2*)(hb + (s3 << 7));
        float2 v4 = *(const float2*)(hb + (s4 << 7));
        float2 v5 = *(const float2*)(hb + (s5 << 7));
        float2 v6 = *(const float2*)(hb + (s6 << 7));
        float2 v7 = *(const float2*)(hb + (s7 << 7));
        a0x += v0.x; a0y += v0.y; a1x += v1.x; a1y += v1.y;
        a2x += v2.x; a2y += v2.y; a3x += v3.x; a3y += v3.y;
        a0x += v4.x; a0y += v4.y; a1x += v5.x; a1y += v5.y;
        a2x += v6.x; a2y += v6.y; a3x += v7.x; a3y += v7.y;
    }
    if (idx + 4 <= end) {
        int s0 = col[idx], s1 = col[idx + 1], s2 = col[idx + 2], s3 = col[idx + 3];
        float2 v0 = *(const float2*)(hb + (s0 << 7));
        float2 v1 = *(const float2*)(hb + (s1 << 7));
        float2 v2 = *(const float2*)(hb + (s2 << 7));
        float2 v3 = *(const float2*)(hb + (s3 << 7));
        a0x += v0.x; a0y += v0.y; a1x += v1.x; a1y += v1.y;
        a2x += v2.x; a2y += v2.y; a3x += v3.x; a3y += v3.y;
        idx += 4;
    }
    for (; idx < end; ++idx) {
        int s = col[idx];
        float2 v = *(const float2*)(hb + (s << 7));
        a0x += v.x; a0y += v.y;
    }
    float2 hv = *(const float2*)(hb + (wid << 7));   // self term (already dinv-scaled)
    float ax = ((a0x + a1x) + (a2x + a3x)) + hv.x;
    float ay = ((a0y + a1y) + (a2y + a3y)) + hv.y;
    float di = dinv[wid];
    ax = fmaf(ax, di, b1[c2]);
    ay = fmaf(ay, di, b1[c2 + 1]);
    float2 o;
    o.x = fmaxf(ax, 0.f);
    o.y = fmaxf(ay, 0.f);
    *(float2*)&out1[(wid << 7) + c2] = o;
}

// ---------------- GEMM 2: h2s = dinv .* (out1 @ W2)  (N x 128 @ 128 x 40) -------

__global__ __launch_bounds__(256) void k_gemm2(const float* __restrict__ xin,
                                               const float* __restrict__ W,
                                               const float* __restrict__ dinv,
                                               float* __restrict__ h, int n) {
    __shared__ float xs[64][129];
    __shared__ float wsh[128 * F_OUT];
    const int tid = threadIdx.x;
    const int bm = blockIdx.x * 64;

    for (int i = tid; i < 128 * F_OUT; i += 256) wsh[i] = W[i];
    for (int i = tid * 4; i < 64 * 128; i += 256 * 4) {
        int r = i >> 7, c = i & 127;
        int gr = bm + r;
        float4 v = (gr < n) ? *(const float4*)&xin[(size_t)gr * F_H + c]
                            : make_float4(0.f, 0.f, 0.f, 0.f);
        xs[r][c] = v.x; xs[r][c + 1] = v.y; xs[r][c + 2] = v.z; xs[r][c + 3] = v.w;
    }
    __syncthreads();

    const int cg = (tid & 7) * 5;    // 8 col-groups x 5 cols = 40
    const int rg = (tid >> 3) * 2;   // 32 row-groups x 2 rows = 64
    float acc[2][5] = {};
    for (int k = 0; k < 128; ++k) {
        float a0 = xs[rg][k], a1 = xs[rg + 1][k];
#pragma unroll
        for (int j = 0; j < 5; ++j) {
            float b = wsh[k * F_OUT + cg + j];
            acc[0][j] = fmaf(a0, b, acc[0][j]);
            acc[1][j] = fmaf(a1, b, acc[1][j]);
        }
    }
#pragma unroll
    for (int i = 0; i < 2; ++i) {
        int gr = bm + rg + i;
        if (gr < n) {
            float d = dinv[gr];
#pragma unroll
            for (int j = 0; j < 5; ++j) h[(size_t)gr * F_OUT + cg + j] = acc[i][j] * d;
        }
    }
}

// -------- Aggregation layer 2 (40 feats): wave/node, 8-deep gather pipeline -----

__global__ __launch_bounds__(256) void k_agg2(const float* __restrict__ h2s,
                                              const int* __restrict__ row_ptr,
                                              const int* __restrict__ col,
                                              const float* __restrict__ dinv,
                                              const float* __restrict__ b2,
                                              float* __restrict__ out, int n) {
    int wid = (blockIdx.x * 256 + threadIdx.x) >> 6;
    int lane = threadIdx.x & 63;
    if (wid >= n) return;
    int beg = row_ptr[wid], end = row_ptr[wid + 1];
    bool act = (lane < F_OUT);
    int lc = act ? lane : 0;
    const float* hb = h2s + lc;

    float a0 = 0.f, a1 = 0.f, a2 = 0.f, a3 = 0.f;
    int idx = beg;
    for (; idx + 8 <= end; idx += 8) {
        int s0 = col[idx],     s1 = col[idx + 1], s2 = col[idx + 2], s3 = col[idx + 3];
        int s4 = col[idx + 4], s5 = col[idx + 5], s6 = col[idx + 6], s7 = col[idx + 7];
        float v0 = hb[s0 * F_OUT], v1 = hb[s1 * F_OUT], v2 = hb[s2 * F_OUT], v3 = hb[s3 * F_OUT];
        float v4 = hb[s4 * F_OUT], v5 = hb[s5 * F_OUT], v6 = hb[s6 * F_OUT], v7 = hb[s7 * F_OUT];
        a0 += v0; a1 += v1; a2 += v2; a3 += v3;
        a0 += v4; a1 += v5; a2 += v6; a3 += v7;
    }
    if (idx + 4 <= end) {
        int s0 = col[idx], s1 = col[idx + 1], s2 = col[idx + 2], s3 = col[idx + 3];
        a0 += hb[s0 * F_OUT]; a1 += hb[s1 * F_OUT];
        a2 += hb[s2 * F_OUT]; a3 += hb[s3 * F_OUT];
        idx += 4;
    }
    for (; idx < end; ++idx) a0 += hb[col[idx] * F_OUT];

    if (act) {
        float acc = ((a0 + a1) + (a2 + a3)) + hb[wid * F_OUT];  // self term
        float di = dinv[wid];
        out[wid * F_OUT + lane] = fmaf(acc, di, b2[lane]);
    }
}

// ---------------- launch ----------------

extern "C" void kernel_launch(void* const* d_in, const int* in_sizes, int n_in,
                              void* d_out, int out_size, void* d_ws, size_t ws_size,
                              hipStream_t stream) {
    const float* x  = (const float*)d_in[0];
    const int*   ei = (const int*)d_in[1];
    const float* W1 = (const float*)d_in[2];
    const float* b1 = (const float*)d_in[3];
    const float* W2 = (const float*)d_in[4];
    const float* b2 = (const float*)d_in[5];
    float* out = (float*)d_out;

    const int N = in_sizes[0] / F_IN;     // 100000
    const int E = in_sizes[1] / 2;        // 1600000
    const int* src = ei;
    const int* dst = ei + E;

    char* ws = (char*)d_ws;
    size_t off = 0;
    auto alloc = [&](size_t bytes) -> void* {
        off = (off + 255) & ~(size_t)255;
        void* p = ws + off;
        off += bytes;
        return p;
    };
    int*   deg     = (int*)  alloc((size_t)N * 4);
    int*   cnt2    = (int*)  alloc((size_t)N * 4);
    float* dinv    = (float*)alloc((size_t)N * 4);
    int*   row_ptr = (int*)  alloc((size_t)(N + 1) * 4);
    int*   bsum    = (int*)  alloc(129 * 4);
    int*   bexcl   = (int*)  alloc(129 * 4);
    int*   col     = (int*)  alloc((size_t)E * 4);
    float* h1      = (float*)alloc((size_t)N * F_H * 4);
    float* out1    = (float*)alloc((size_t)N * F_H * 4);
    float* h2      = h1;   // h1 dead after k_agg1 -> reuse (N*40 <= N*128)

    const int gN  = (N + 255) / 256;
    const int gE  = (E + 255) / 256;
    const int nb  = (N + 1023) / 1024;   // 98 <= 128

    hipMemsetAsync(deg,  0, (size_t)N * 4, stream);
    hipMemsetAsync(cnt2, 0, (size_t)N * 4, stream);
    k_count<<<gE, 256, 0, stream>>>(dst, deg, E);
    k_dinv <<<gN, 256, 0, stream>>>(deg, dinv, N);
    k_scan1<<<nb, 1024, 0, stream>>>(deg, row_ptr, bsum, N);
    k_scan2<<<1, 128, 0, stream>>>(bsum, bexcl, nb);
    k_scan3<<<gN, 256, 0, stream>>>(row_ptr, bexcl, N, nb);
    k_fill <<<gE, 256, 0, stream>>>(src, dst, row_ptr, cnt2, col, E);

    k_gemm1<<<(N + 127) / 128, 256, 0, stream>>>(x, W1, dinv, h1, N);
    k_agg1 <<<(N + 3) / 4, 256, 0, stream>>>(h1, row_ptr, col, dinv, b1, out1, N);
    k_gemm2<<<(N + 63) / 64, 256, 0, stream>>>(out1, W2, dinv, h2, N);
    k_agg2 <<<(N + 3) / 4, 256, 0, stream>>>(h2, row_ptr, col, dinv, b2, out, N);
}

// Round 3
// 459.514 us; speedup vs baseline: 1.3534x; 1.0868x over previous
//
#include <hip/hip_runtime.h>

// GCN forward: 2x (GEMM + symmetric-normalized aggregation), fp32.
// CSR built per call (count -> scan -> fill).
// GEMM epilogues pre-scale rows by dinv[row]; aggregation is pure gather-add:
//   out[i] = d_i * (sum_{s in N(i)} h_s[s] + h_s[i]) + b
// GEMMs: W panel in LDS only (32KB / 20KB), x streamed global->reg, high occupancy.
// Aggregations: multi-edge-per-wave gathers (2x float4 / 3x float2), shfl combine.

#define F_IN  128
#define F_H   128
#define F_OUT 40

// ---------------- CSR build ----------------

__global__ void k_count(const int* __restrict__ dst, int* __restrict__ deg, int e) {
    int i = blockIdx.x * 256 + threadIdx.x;
    if (i < e) atomicAdd(&deg[dst[i]], 1);
}

__global__ void k_dinv(const int* __restrict__ deg, float* __restrict__ dinv, int n) {
    int i = blockIdx.x * 256 + threadIdx.x;
    if (i < n) dinv[i] = rsqrtf((float)deg[i] + 1.0f);   // +1 self-loop
}

__global__ void k_scan1(const int* __restrict__ cnt, int* __restrict__ out,
                        int* __restrict__ bsum, int n) {
    __shared__ int s[1024];
    int i = blockIdx.x * 1024 + threadIdx.x;
    int v = (i < n) ? cnt[i] : 0;
    s[threadIdx.x] = v;
    __syncthreads();
    for (int off = 1; off < 1024; off <<= 1) {
        int t = (threadIdx.x >= off) ? s[threadIdx.x - off] : 0;
        __syncthreads();
        s[threadIdx.x] += t;
        __syncthreads();
    }
    if (i < n) out[i] = s[threadIdx.x] - v;
    if (threadIdx.x == 1023) bsum[blockIdx.x] = s[1023];
}

__global__ void k_scan2(const int* __restrict__ bsum, int* __restrict__ bexcl, int nb) {
    __shared__ int s[128];
    int v = (threadIdx.x < nb) ? bsum[threadIdx.x] : 0;
    s[threadIdx.x] = v;
    __syncthreads();
    for (int off = 1; off < 128; off <<= 1) {
        int t = (threadIdx.x >= off) ? s[threadIdx.x - off] : 0;
        __syncthreads();
        s[threadIdx.x] += t;
        __syncthreads();
    }
    if (threadIdx.x < nb) bexcl[threadIdx.x] = s[threadIdx.x] - v;
    if (threadIdx.x == 127) bexcl[nb] = s[127];
}

__global__ void k_scan3(int* __restrict__ out, const int* __restrict__ bexcl, int n, int nb) {
    int i = blockIdx.x * 256 + threadIdx.x;
    if (i < n) out[i] += bexcl[i >> 10];
    if (i == 0) out[n] = bexcl[nb];
}

__global__ void k_fill(const int* __restrict__ src, const int* __restrict__ dst,
                       const int* __restrict__ row_ptr, int* __restrict__ cnt2,
                       int* __restrict__ col, int e) {
    int i = blockIdx.x * 256 + threadIdx.x;
    if (i < e) {
        int d = dst[i];
        int pos = row_ptr[d] + atomicAdd(&cnt2[d], 1);
        col[pos] = src[i];
    }
}

// ---- GEMM 1: h1s = dinv .* (x @ W1), N x 128 @ 128 x 128 ----
// 64 rows/block, thread = 8 rows x 4 cols. W half-panel (64x128 = 32KB) in LDS;
// x streamed global->reg, double-buffered 4-wide k chunks.

__global__ __launch_bounds__(256) void k_gemm1(const float* __restrict__ x,
                                               const float* __restrict__ W,
                                               const float* __restrict__ dinv,
                                               float* __restrict__ h, int n) {
    __shared__ float wsh[64 * 128];
    const int tid = threadIdx.x;
    const int c0  = (tid & 31) * 4;          // 32 col-groups x 4 cols
    const int r0  = blockIdx.x * 64 + (tid >> 5) * 8;   // 8 row-groups x 8 rows

    int xoff[8];
#pragma unroll
    for (int i = 0; i < 8; ++i) {
        int gr = r0 + i;
        if (gr > n - 1) gr = n - 1;          // clamp; stores are guarded
        xoff[i] = gr * F_IN;
    }

    float acc[8][4] = {};
#pragma unroll
    for (int half = 0; half < 2; ++half) {
        const int kb = half * 64;
        __syncthreads();                      // previous compute done before overwrite
        for (int i = tid * 4; i < 64 * 128; i += 1024)
            *(float4*)&wsh[i] = *(const float4*)&W[kb * 128 + i];
        __syncthreads();

        float4 xa[8], xb[8];
#pragma unroll
        for (int i = 0; i < 8; ++i) xa[i] = *(const float4*)&x[xoff[i] + kb];

        for (int kk = 0; kk < 64; kk += 8) {
            // prefetch chunk kk+4 into xb
#pragma unroll
            for (int i = 0; i < 8; ++i) xb[i] = *(const float4*)&x[xoff[i] + kb + kk + 4];
            // compute chunk kk (xa)
#pragma unroll
            for (int k4 = 0; k4 < 4; ++k4) {
                float4 bv = *(const float4*)&wsh[(kk + k4) * 128 + c0];
#pragma unroll
                for (int i = 0; i < 8; ++i) {
                    float a = ((const float*)&xa[i])[k4];
                    acc[i][0] = fmaf(a, bv.x, acc[i][0]);
                    acc[i][1] = fmaf(a, bv.y, acc[i][1]);
                    acc[i][2] = fmaf(a, bv.z, acc[i][2]);
                    acc[i][3] = fmaf(a, bv.w, acc[i][3]);
                }
            }
            // prefetch chunk kk+8 into xa
            if (kk + 8 < 64) {
#pragma unroll
                for (int i = 0; i < 8; ++i) xa[i] = *(const float4*)&x[xoff[i] + kb + kk + 8];
            }
            // compute chunk kk+4 (xb)
#pragma unroll
            for (int k4 = 0; k4 < 4; ++k4) {
                float4 bv = *(const float4*)&wsh[(kk + 4 + k4) * 128 + c0];
#pragma unroll
                for (int i = 0; i < 8; ++i) {
                    float a = ((const float*)&xb[i])[k4];
                    acc[i][0] = fmaf(a, bv.x, acc[i][0]);
                    acc[i][1] = fmaf(a, bv.y, acc[i][1]);
                    acc[i][2] = fmaf(a, bv.z, acc[i][2]);
                    acc[i][3] = fmaf(a, bv.w, acc[i][3]);
                }
            }
        }
    }

#pragma unroll
    for (int i = 0; i < 8; ++i) {
        int gr = r0 + i;
        if (gr < n) {
            float d = dinv[gr];
            float4 o = make_float4(acc[i][0] * d, acc[i][1] * d,
                                   acc[i][2] * d, acc[i][3] * d);
            *(float4*)&h[gr * F_H + c0] = o;
        }
    }
}

// ---- Aggregation layer 1 (128 feats): wave/node, 2 edges per load slot ----
// lanes 0-31 take even-offset edges, 32-63 odd; each lane float4 over 4 cols.

__global__ __launch_bounds__(256) void k_agg1(const float* __restrict__ h1s,
                                              const int* __restrict__ row_ptr,
                                              const int* __restrict__ col,
                                              const float* __restrict__ dinv,
                                              const float* __restrict__ b1,
                                              float* __restrict__ out1, int n) {
    int wid = (blockIdx.x * 256 + threadIdx.x) >> 6;
    int lane = threadIdx.x & 63;
    if (wid >= n) return;
    const int half = lane >> 5;
    const int c4 = (lane & 31) * 4;
    const float* hb = h1s + c4;
    int beg = row_ptr[wid], end = row_ptr[wid + 1];

    float4 a0 = {0,0,0,0}, a1 = {0,0,0,0}, a2 = {0,0,0,0}, a3 = {0,0,0,0};
    int idx = beg + half;                 // this half's edge subsequence (stride 2)
    for (; idx + 6 < end; idx += 8) {     // 4 edges/half = 8 edges/wave per iter
        int s0 = col[idx], s1 = col[idx + 2], s2 = col[idx + 4], s3 = col[idx + 6];
        float4 v0 = *(const float4*)(hb + (s0 << 7));
        float4 v1 = *(const float4*)(hb + (s1 << 7));
        float4 v2 = *(const float4*)(hb + (s2 << 7));
        float4 v3 = *(const float4*)(hb + (s3 << 7));
        a0.x += v0.x; a0.y += v0.y; a0.z += v0.z; a0.w += v0.w;
        a1.x += v1.x; a1.y += v1.y; a1.z += v1.z; a1.w += v1.w;
        a2.x += v2.x; a2.y += v2.y; a2.z += v2.z; a2.w += v2.w;
        a3.x += v3.x; a3.y += v3.y; a3.z += v3.z; a3.w += v3.w;
    }
    for (; idx < end; idx += 2) {
        int s = col[idx];
        float4 v = *(const float4*)(hb + (s << 7));
        a0.x += v.x; a0.y += v.y; a0.z += v.z; a0.w += v.w;
    }
    float4 t;
    t.x = (a0.x + a1.x) + (a2.x + a3.x);
    t.y = (a0.y + a1.y) + (a2.y + a3.y);
    t.z = (a0.z + a1.z) + (a2.z + a3.z);
    t.w = (a0.w + a1.w) + (a2.w + a3.w);
    // cross-half combine
    t.x += __shfl(t.x, lane ^ 32);
    t.y += __shfl(t.y, lane ^ 32);
    t.z += __shfl(t.z, lane ^ 32);
    t.w += __shfl(t.w, lane ^ 32);
    if (half == 0) {
        float4 hv = *(const float4*)(hb + (wid << 7));   // self (already dinv-scaled)
        float di = dinv[wid];
        float4 bv = *(const float4*)&b1[c4];
        float4 o;
        o.x = fmaxf(fmaf(t.x + hv.x, di, bv.x), 0.f);
        o.y = fmaxf(fmaf(t.y + hv.y, di, bv.y), 0.f);
        o.z = fmaxf(fmaf(t.z + hv.z, di, bv.z), 0.f);
        o.w = fmaxf(fmaf(t.w + hv.w, di, bv.w), 0.f);
        *(float4*)&out1[(wid << 7) + c4] = o;
    }
}

// ---- GEMM 2: h2s = dinv .* (out1 @ W2), N x 128 @ 128 x 40 ----
// 128 rows/block, thread = 4 rows x 5 cols. Full W2 (20KB) in LDS.

__global__ __launch_bounds__(256) void k_gemm2(const float* __restrict__ xin,
                                               const float* __restrict__ W,
                                               const float* __restrict__ dinv,
                                               float* __restrict__ h, int n) {
    __shared__ float wsh[128 * F_OUT];
    const int tid = threadIdx.x;
    const int c0  = (tid & 7) * 5;            // 8 col-groups x 5 cols
    const int r0  = blockIdx.x * 128 + (tid >> 3) * 4;   // 32 slots x 4 rows

    for (int i = tid * 4; i < 128 * F_OUT; i += 1024)
        *(float4*)&wsh[i] = *(const float4*)&W[i];

    int xoff[4];
#pragma unroll
    for (int i = 0; i < 4; ++i) {
        int gr = r0 + i;
        if (gr > n - 1) gr = n - 1;
        xoff[i] = gr * F_H;
    }
    __syncthreads();

    float acc[4][5] = {};
    float4 xa[4], xb[4];
#pragma unroll
    for (int i = 0; i < 4; ++i) xa[i] = *(const float4*)&xin[xoff[i]];

    for (int kk = 0; kk < 128; kk += 8) {
#pragma unroll
        for (int i = 0; i < 4; ++i) xb[i] = *(const float4*)&xin[xoff[i] + kk + 4];
#pragma unroll
        for (int k4 = 0; k4 < 4; ++k4) {
            float bv[5];
#pragma unroll
            for (int j = 0; j < 5; ++j) bv[j] = wsh[(kk + k4) * F_OUT + c0 + j];
#pragma unroll
            for (int i = 0; i < 4; ++i) {
                float a = ((const float*)&xa[i])[k4];
#pragma unroll
                for (int j = 0; j < 5; ++j) acc[i][j] = fmaf(a, bv[j], acc[i][j]);
            }
        }
        if (kk + 8 < 128) {
#pragma unroll
            for (int i = 0; i < 4; ++i) xa[i] = *(const float4*)&xin[xoff[i] + kk + 8];
        }
#pragma unroll
        for (int k4 = 0; k4 < 4; ++k4) {
            float bv[5];
#pragma unroll
            for (int j = 0; j < 5; ++j) bv[j] = wsh[(kk + 4 + k4) * F_OUT + c0 + j];
#pragma unroll
            for (int i = 0; i < 4; ++i) {
                float a = ((const float*)&xb[i])[k4];
#pragma unroll
                for (int j = 0; j < 5; ++j) acc[i][j] = fmaf(a, bv[j], acc[i][j]);
            }
        }
    }

#pragma unroll
    for (int i = 0; i < 4; ++i) {
        int gr = r0 + i;
        if (gr < n) {
            float d = dinv[gr];
#pragma unroll
            for (int j = 0; j < 5; ++j) h[gr * F_OUT + c0 + j] = acc[i][j] * d;
        }
    }
}

// ---- Aggregation layer 2 (40 feats): wave/node, 3 edges per load slot ----
// lanes 0-19/20-39/40-59 take edge subsequences stride 3; float2 over 2 cols.

__global__ __launch_bounds__(256) void k_agg2(const float* __restrict__ h2s,
                                              const int* __restrict__ row_ptr,
                                              const int* __restrict__ col,
                                              const float* __restrict__ dinv,
                                              const float* __restrict__ b2,
                                              float* __restrict__ out, int n) {
    int wid = (blockIdx.x * 256 + threadIdx.x) >> 6;
    int lane = threadIdx.x & 63;
    if (wid >= n) return;
    int third = lane / 20;                    // 0,1,2 (3 for lanes 60-63)
    bool act = (third < 3);
    int c2 = (lane - third * 20) * 2;
    const float* hb = h2s + (act ? c2 : 0);
    int beg = row_ptr[wid], end = row_ptr[wid + 1];

    float2 a0 = {0,0}, a1 = {0,0}, a2 = {0,0}, a3 = {0,0};
    int idx = act ? (beg + third) : end;
    for (; idx + 9 < end; idx += 12) {        // 4 edges/third = 12 edges/wave
        int s0 = col[idx], s1 = col[idx + 3], s2 = col[idx + 6], s3 = col[idx + 9];
        float2 v0 = *(const float2*)(hb + s0 * F_OUT);
        float2 v1 = *(const float2*)(hb + s1 * F_OUT);
        float2 v2 = *(const float2*)(hb + s2 * F_OUT);
        float2 v3 = *(const float2*)(hb + s3 * F_OUT);
        a0.x += v0.x; a0.y += v0.y;  a1.x += v1.x; a1.y += v1.y;
        a2.x += v2.x; a2.y += v2.y;  a3.x += v3.x; a3.y += v3.y;
    }
    for (; idx < end; idx += 3) {
        int s = col[idx];
        float2 v = *(const float2*)(hb + s * F_OUT);
        a0.x += v.x; a0.y += v.y;
    }
    float2 t;
    t.x = (a0.x + a1.x) + (a2.x + a3.x);
    t.y = (a0.y + a1.y) + (a2.y + a3.y);
    t.x += __shfl(t.x, lane + 20) + __shfl(t.x, lane + 40);
    t.y += __shfl(t.y, lane + 20) + __shfl(t.y, lane + 40);
    if (third == 0) {
        float2 hv = *(const float2*)(hb + wid * F_OUT);  // self
        float di = dinv[wid];
        float2 o;
        o.x = fmaf(t.x + hv.x, di, b2[c2]);
        o.y = fmaf(t.y + hv.y, di, b2[c2 + 1]);
        *(float2*)&out[wid * F_OUT + c2] = o;
    }
}

// ---------------- launch ----------------

extern "C" void kernel_launch(void* const* d_in, const int* in_sizes, int n_in,
                              void* d_out, int out_size, void* d_ws, size_t ws_size,
                              hipStream_t stream) {
    const float* x  = (const float*)d_in[0];
    const int*   ei = (const int*)d_in[1];
    const float* W1 = (const float*)d_in[2];
    const float* b1 = (const float*)d_in[3];
    const float* W2 = (const float*)d_in[4];
    const float* b2 = (const float*)d_in[5];
    float* out = (float*)d_out;

    const int N = in_sizes[0] / F_IN;     // 100000
    const int E = in_sizes[1] / 2;        // 1600000
    const int* src = ei;
    const int* dst = ei + E;

    char* ws = (char*)d_ws;
    size_t off = 0;
    auto alloc = [&](size_t bytes) -> void* {
        off = (off + 255) & ~(size_t)255;
        void* p = ws + off;
        off += bytes;
        return p;
    };
    int*   deg     = (int*)  alloc((size_t)N * 4);
    int*   cnt2    = (int*)  alloc((size_t)N * 4);
    float* dinv    = (float*)alloc((size_t)N * 4);
    int*   row_ptr = (int*)  alloc((size_t)(N + 1) * 4);
    int*   bsum    = (int*)  alloc(129 * 4);
    int*   bexcl   = (int*)  alloc(129 * 4);
    int*   col     = (int*)  alloc((size_t)E * 4);
    float* h1      = (float*)alloc((size_t)N * F_H * 4);
    float* out1    = (float*)alloc((size_t)N * F_H * 4);
    float* h2      = h1;   // h1 dead after k_agg1 -> reuse (N*40 <= N*128)

    const int gN  = (N + 255) / 256;
    const int gE  = (E + 255) / 256;
    const int nb  = (N + 1023) / 1024;   // 98 <= 128

    hipMemsetAsync(deg,  0, (size_t)N * 4, stream);
    hipMemsetAsync(cnt2, 0, (size_t)N * 4, stream);
    k_count<<<gE, 256, 0, stream>>>(dst, deg, E);
    k_dinv <<<gN, 256, 0, stream>>>(deg, dinv, N);
    k_scan1<<<nb, 1024, 0, stream>>>(deg, row_ptr, bsum, N);
    k_scan2<<<1, 128, 0, stream>>>(bsum, bexcl, nb);
    k_scan3<<<gN, 256, 0, stream>>>(row_ptr, bexcl, N, nb);
    k_fill <<<gE, 256, 0, stream>>>(src, dst, row_ptr, cnt2, col, E);

    k_gemm1<<<(N + 63) / 64, 256, 0, stream>>>(x, W1, dinv, h1, N);
    k_agg1 <<<(N + 3) / 4, 256, 0, stream>>>(h1, row_ptr, col, dinv, b1, out1, N);
    k_gemm2<<<(N + 127) / 128, 256, 0, stream>>>(out1, W2, dinv, h2, N);
    k_agg2 <<<(N + 3) / 4, 256, 0, stream>>>(h2, row_ptr, col, dinv, b2, out, N);
}

// Round 4
// 376.619 us; speedup vs baseline: 1.6513x; 1.2201x over previous
//
#include <hip/hip_runtime.h>
#include <hip/hip_fp16.h>

// GCN forward: 2x (GEMM + symmetric-normalized aggregation), fp32 in/out.
// CSR built per call (count -> scan -> fill).
// GEMM epilogues pre-scale rows by dinv[row] and store fp16 (internal only):
//   out[i] = d_i * (sum_{s in N(i)} h_s[s] + h_s[i]) + b
// Aggregations gather fp16 rows (half the bytes of fp32), accumulate fp32.

#define F_IN  128
#define F_H   128
#define F_OUT 40

// ---------------- CSR build ----------------

__global__ void k_count(const int* __restrict__ dst, int* __restrict__ deg, int e) {
    int i = blockIdx.x * 256 + threadIdx.x;
    if (i < e) atomicAdd(&deg[dst[i]], 1);
}

__global__ void k_dinv(const int* __restrict__ deg, float* __restrict__ dinv, int n) {
    int i = blockIdx.x * 256 + threadIdx.x;
    if (i < n) dinv[i] = rsqrtf((float)deg[i] + 1.0f);   // +1 self-loop
}

__global__ void k_scan1(const int* __restrict__ cnt, int* __restrict__ out,
                        int* __restrict__ bsum, int n) {
    __shared__ int s[1024];
    int i = blockIdx.x * 1024 + threadIdx.x;
    int v = (i < n) ? cnt[i] : 0;
    s[threadIdx.x] = v;
    __syncthreads();
    for (int off = 1; off < 1024; off <<= 1) {
        int t = (threadIdx.x >= off) ? s[threadIdx.x - off] : 0;
        __syncthreads();
        s[threadIdx.x] += t;
        __syncthreads();
    }
    if (i < n) out[i] = s[threadIdx.x] - v;
    if (threadIdx.x == 1023) bsum[blockIdx.x] = s[1023];
}

__global__ void k_scan2(const int* __restrict__ bsum, int* __restrict__ bexcl, int nb) {
    __shared__ int s[128];
    int v = (threadIdx.x < nb) ? bsum[threadIdx.x] : 0;
    s[threadIdx.x] = v;
    __syncthreads();
    for (int off = 1; off < 128; off <<= 1) {
        int t = (threadIdx.x >= off) ? s[threadIdx.x - off] : 0;
        __syncthreads();
        s[threadIdx.x] += t;
        __syncthreads();
    }
    if (threadIdx.x < nb) bexcl[threadIdx.x] = s[threadIdx.x] - v;
    if (threadIdx.x == 127) bexcl[nb] = s[127];
}

__global__ void k_scan3(int* __restrict__ out, const int* __restrict__ bexcl, int n, int nb) {
    int i = blockIdx.x * 256 + threadIdx.x;
    if (i < n) out[i] += bexcl[i >> 10];
    if (i == 0) out[n] = bexcl[nb];
}

__global__ void k_fill(const int* __restrict__ src, const int* __restrict__ dst,
                       const int* __restrict__ row_ptr, int* __restrict__ cnt2,
                       int* __restrict__ col, int e) {
    int i = blockIdx.x * 256 + threadIdx.x;
    if (i < e) {
        int d = dst[i];
        int pos = row_ptr[d] + atomicAdd(&cnt2[d], 1);
        col[pos] = src[i];
    }
}

// ---- GEMM 1: h1s = fp16( dinv .* (x @ W1) ), N x 128 @ 128 x 128 ----
// 64 rows/block, thread = 8 rows x 4 cols. W half-panel (64x128 = 32KB) in LDS;
// x streamed global->reg, double-buffered 4-wide k chunks.

__global__ __launch_bounds__(256) void k_gemm1(const float* __restrict__ x,
                                               const float* __restrict__ W,
                                               const float* __restrict__ dinv,
                                               __half* __restrict__ h, int n) {
    __shared__ float wsh[64 * 128];
    const int tid = threadIdx.x;
    const int c0  = (tid & 31) * 4;          // 32 col-groups x 4 cols
    const int r0  = blockIdx.x * 64 + (tid >> 5) * 8;   // 8 row-groups x 8 rows

    int xoff[8];
#pragma unroll
    for (int i = 0; i < 8; ++i) {
        int gr = r0 + i;
        if (gr > n - 1) gr = n - 1;          // clamp; stores are guarded
        xoff[i] = gr * F_IN;
    }

    float acc[8][4] = {};
#pragma unroll
    for (int half = 0; half < 2; ++half) {
        const int kb = half * 64;
        __syncthreads();
        for (int i = tid * 4; i < 64 * 128; i += 1024)
            *(float4*)&wsh[i] = *(const float4*)&W[kb * 128 + i];
        __syncthreads();

        float4 xa[8], xb[8];
#pragma unroll
        for (int i = 0; i < 8; ++i) xa[i] = *(const float4*)&x[xoff[i] + kb];

        for (int kk = 0; kk < 64; kk += 8) {
#pragma unroll
            for (int i = 0; i < 8; ++i) xb[i] = *(const float4*)&x[xoff[i] + kb + kk + 4];
#pragma unroll
            for (int k4 = 0; k4 < 4; ++k4) {
                float4 bv = *(const float4*)&wsh[(kk + k4) * 128 + c0];
#pragma unroll
                for (int i = 0; i < 8; ++i) {
                    float a = ((const float*)&xa[i])[k4];
                    acc[i][0] = fmaf(a, bv.x, acc[i][0]);
                    acc[i][1] = fmaf(a, bv.y, acc[i][1]);
                    acc[i][2] = fmaf(a, bv.z, acc[i][2]);
                    acc[i][3] = fmaf(a, bv.w, acc[i][3]);
                }
            }
            if (kk + 8 < 64) {
#pragma unroll
                for (int i = 0; i < 8; ++i) xa[i] = *(const float4*)&x[xoff[i] + kb + kk + 8];
            }
#pragma unroll
            for (int k4 = 0; k4 < 4; ++k4) {
                float4 bv = *(const float4*)&wsh[(kk + 4 + k4) * 128 + c0];
#pragma unroll
                for (int i = 0; i < 8; ++i) {
                    float a = ((const float*)&xb[i])[k4];
                    acc[i][0] = fmaf(a, bv.x, acc[i][0]);
                    acc[i][1] = fmaf(a, bv.y, acc[i][1]);
                    acc[i][2] = fmaf(a, bv.z, acc[i][2]);
                    acc[i][3] = fmaf(a, bv.w, acc[i][3]);
                }
            }
        }
    }

#pragma unroll
    for (int i = 0; i < 8; ++i) {
        int gr = r0 + i;
        if (gr < n) {
            float d = dinv[gr];
            __half2 p0 = __floats2half2_rn(acc[i][0] * d, acc[i][1] * d);
            __half2 p1 = __floats2half2_rn(acc[i][2] * d, acc[i][3] * d);
            uint2 pk;
            pk.x = *(unsigned int*)&p0;
            pk.y = *(unsigned int*)&p1;
            *(uint2*)&h[gr * F_H + c0] = pk;
        }
    }
}

// ---- Aggregation layer 1 (128 feats, fp16 rows): wave/node ----
// lane owns feature pair [2*lane, 2*lane+1]; 8 edges in flight per iter.

__global__ __launch_bounds__(256) void k_agg1(const __half* __restrict__ h1s,
                                              const int* __restrict__ row_ptr,
                                              const int* __restrict__ col,
                                              const float* __restrict__ dinv,
                                              const float* __restrict__ b1,
                                              float* __restrict__ out1, int n) {
    int wid = (blockIdx.x * 256 + threadIdx.x) >> 6;
    int lane = threadIdx.x & 63;
    if (wid >= n) return;
    int beg = row_ptr[wid], end = row_ptr[wid + 1];
    const __half2* hb = (const __half2*)h1s + lane;   // row stride 64 half2

    float a0x = 0.f, a0y = 0.f, a1x = 0.f, a1y = 0.f;
    float a2x = 0.f, a2y = 0.f, a3x = 0.f, a3y = 0.f;
    int idx = beg;
    for (; idx + 8 <= end; idx += 8) {
        int s0 = col[idx],     s1 = col[idx + 1], s2 = col[idx + 2], s3 = col[idx + 3];
        int s4 = col[idx + 4], s5 = col[idx + 5], s6 = col[idx + 6], s7 = col[idx + 7];
        float2 v0 = __half22float2(hb[s0 << 6]);
        float2 v1 = __half22float2(hb[s1 << 6]);
        float2 v2 = __half22float2(hb[s2 << 6]);
        float2 v3 = __half22float2(hb[s3 << 6]);
        float2 v4 = __half22float2(hb[s4 << 6]);
        float2 v5 = __half22float2(hb[s5 << 6]);
        float2 v6 = __half22float2(hb[s6 << 6]);
        float2 v7 = __half22float2(hb[s7 << 6]);
        a0x += v0.x; a0y += v0.y; a1x += v1.x; a1y += v1.y;
        a2x += v2.x; a2y += v2.y; a3x += v3.x; a3y += v3.y;
        a0x += v4.x; a0y += v4.y; a1x += v5.x; a1y += v5.y;
        a2x += v6.x; a2y += v6.y; a3x += v7.x; a3y += v7.y;
    }
    if (idx + 4 <= end) {
        int s0 = col[idx], s1 = col[idx + 1], s2 = col[idx + 2], s3 = col[idx + 3];
        float2 v0 = __half22float2(hb[s0 << 6]);
        float2 v1 = __half22float2(hb[s1 << 6]);
        float2 v2 = __half22float2(hb[s2 << 6]);
        float2 v3 = __half22float2(hb[s3 << 6]);
        a0x += v0.x; a0y += v0.y; a1x += v1.x; a1y += v1.y;
        a2x += v2.x; a2y += v2.y; a3x += v3.x; a3y += v3.y;
        idx += 4;
    }
    for (; idx < end; ++idx) {
        float2 v = __half22float2(hb[col[idx] << 6]);
        a0x += v.x; a0y += v.y;
    }
    float2 hv = __half22float2(hb[wid << 6]);   // self (already dinv-scaled)
    float ax = (((a0x + a1x) + (a2x + a3x)) + hv.x);
    float ay = (((a0y + a1y) + (a2y + a3y)) + hv.y);
    float di = dinv[wid];
    int c2 = lane * 2;
    ax = fmaf(ax, di, b1[c2]);
    ay = fmaf(ay, di, b1[c2 + 1]);
    float2 o;
    o.x = fmaxf(ax, 0.f);
    o.y = fmaxf(ay, 0.f);
    *(float2*)&out1[(wid << 7) + c2] = o;
}

// ---- GEMM 2: h2s = fp16( dinv .* (out1 @ W2) ), N x 128 @ 128 x 40 ----

__global__ __launch_bounds__(256) void k_gemm2(const float* __restrict__ xin,
                                               const float* __restrict__ W,
                                               const float* __restrict__ dinv,
                                               __half* __restrict__ h, int n) {
    __shared__ float wsh[128 * F_OUT];
    const int tid = threadIdx.x;
    const int c0  = (tid & 7) * 5;            // 8 col-groups x 5 cols
    const int r0  = blockIdx.x * 128 + (tid >> 3) * 4;   // 32 slots x 4 rows

    for (int i = tid * 4; i < 128 * F_OUT; i += 1024)
        *(float4*)&wsh[i] = *(const float4*)&W[i];

    int xoff[4];
#pragma unroll
    for (int i = 0; i < 4; ++i) {
        int gr = r0 + i;
        if (gr > n - 1) gr = n - 1;
        xoff[i] = gr * F_H;
    }
    __syncthreads();

    float acc[4][5] = {};
    float4 xa[4], xb[4];
#pragma unroll
    for (int i = 0; i < 4; ++i) xa[i] = *(const float4*)&xin[xoff[i]];

    for (int kk = 0; kk < 128; kk += 8) {
#pragma unroll
        for (int i = 0; i < 4; ++i) xb[i] = *(const float4*)&xin[xoff[i] + kk + 4];
#pragma unroll
        for (int k4 = 0; k4 < 4; ++k4) {
            float bv[5];
#pragma unroll
            for (int j = 0; j < 5; ++j) bv[j] = wsh[(kk + k4) * F_OUT + c0 + j];
#pragma unroll
            for (int i = 0; i < 4; ++i) {
                float a = ((const float*)&xa[i])[k4];
#pragma unroll
                for (int j = 0; j < 5; ++j) acc[i][j] = fmaf(a, bv[j], acc[i][j]);
            }
        }
        if (kk + 8 < 128) {
#pragma unroll
            for (int i = 0; i < 4; ++i) xa[i] = *(const float4*)&xin[xoff[i] + kk + 8];
        }
#pragma unroll
        for (int k4 = 0; k4 < 4; ++k4) {
            float bv[5];
#pragma unroll
            for (int j = 0; j < 5; ++j) bv[j] = wsh[(kk + 4 + k4) * F_OUT + c0 + j];
#pragma unroll
            for (int i = 0; i < 4; ++i) {
                float a = ((const float*)&xb[i])[k4];
#pragma unroll
                for (int j = 0; j < 5; ++j) acc[i][j] = fmaf(a, bv[j], acc[i][j]);
            }
        }
    }

#pragma unroll
    for (int i = 0; i < 4; ++i) {
        int gr = r0 + i;
        if (gr < n) {
            float d = dinv[gr];
#pragma unroll
            for (int j = 0; j < 5; ++j)
                h[gr * F_OUT + c0 + j] = __float2half_rn(acc[i][j] * d);
        }
    }
}

// ---- Aggregation layer 2 (40 feats, fp16 rows): wave/node, 3 edges/slot ----
// lanes in thirds of 20; lane owns feature pair; 12 edges per iter.

__global__ __launch_bounds__(256) void k_agg2(const __half* __restrict__ h2s,
                                              const int* __restrict__ row_ptr,
                                              const int* __restrict__ col,
                                              const float* __restrict__ dinv,
                                              const float* __restrict__ b2,
                                              float* __restrict__ out, int n) {
    int wid = (blockIdx.x * 256 + threadIdx.x) >> 6;
    int lane = threadIdx.x & 63;
    if (wid >= n) return;
    int third = lane / 20;                    // 0,1,2 (3 for lanes 60-63)
    bool act = (third < 3);
    int ll = act ? (lane - third * 20) : 0;   // half2 index in row [0,20)
    const __half2* hb = (const __half2*)h2s + ll;   // row stride 20 half2
    int beg = row_ptr[wid], end = row_ptr[wid + 1];

    float a0x = 0.f, a0y = 0.f, a1x = 0.f, a1y = 0.f;
    float a2x = 0.f, a2y = 0.f, a3x = 0.f, a3y = 0.f;
    int idx = act ? (beg + third) : end;
    for (; idx + 9 < end; idx += 12) {        // 4 edges/third = 12 edges/wave
        int s0 = col[idx], s1 = col[idx + 3], s2 = col[idx + 6], s3 = col[idx + 9];
        float2 v0 = __half22float2(hb[s0 * 20]);
        float2 v1 = __half22float2(hb[s1 * 20]);
        float2 v2 = __half22float2(hb[s2 * 20]);
        float2 v3 = __half22float2(hb[s3 * 20]);
        a0x += v0.x; a0y += v0.y; a1x += v1.x; a1y += v1.y;
        a2x += v2.x; a2y += v2.y; a3x += v3.x; a3y += v3.y;
    }
    for (; idx < end; idx += 3) {
        float2 v = __half22float2(hb[col[idx] * 20]);
        a0x += v.x; a0y += v.y;
    }
    float tx = (a0x + a1x) + (a2x + a3x);
    float ty = (a0y + a1y) + (a2y + a3y);
    tx += __shfl(tx, lane + 20) + __shfl(tx, lane + 40);
    ty += __shfl(ty, lane + 20) + __shfl(ty, lane + 40);
    if (third == 0) {
        float2 hv = __half22float2(hb[wid * 20]);  // self
        float di = dinv[wid];
        int c2 = ll * 2;
        float2 o;
        o.x = fmaf(tx + hv.x, di, b2[c2]);
        o.y = fmaf(ty + hv.y, di, b2[c2 + 1]);
        *(float2*)&out[wid * F_OUT + c2] = o;
    }
}

// ---------------- launch ----------------

extern "C" void kernel_launch(void* const* d_in, const int* in_sizes, int n_in,
                              void* d_out, int out_size, void* d_ws, size_t ws_size,
                              hipStream_t stream) {
    const float* x  = (const float*)d_in[0];
    const int*   ei = (const int*)d_in[1];
    const float* W1 = (const float*)d_in[2];
    const float* b1 = (const float*)d_in[3];
    const float* W2 = (const float*)d_in[4];
    const float* b2 = (const float*)d_in[5];
    float* out = (float*)d_out;

    const int N = in_sizes[0] / F_IN;     // 100000
    const int E = in_sizes[1] / 2;        // 1600000
    const int* src = ei;
    const int* dst = ei + E;

    char* ws = (char*)d_ws;
    size_t off = 0;
    auto alloc = [&](size_t bytes) -> void* {
        off = (off + 255) & ~(size_t)255;
        void* p = ws + off;
        off += bytes;
        return p;
    };
    int*    deg     = (int*)   alloc((size_t)N * 4);
    int*    cnt2    = (int*)   alloc((size_t)N * 4);
    float*  dinv    = (float*) alloc((size_t)N * 4);
    int*    row_ptr = (int*)   alloc((size_t)(N + 1) * 4);
    int*    bsum    = (int*)   alloc(129 * 4);
    int*    bexcl   = (int*)   alloc(129 * 4);
    int*    col     = (int*)   alloc((size_t)E * 4);
    __half* h1s     = (__half*)alloc((size_t)N * F_H * 2);
    float*  out1    = (float*) alloc((size_t)N * F_H * 4);
    __half* h2s     = h1s;     // h1s dead after k_agg1 -> reuse (N*40*2 <= N*128*2)

    const int gN  = (N + 255) / 256;
    const int gE  = (E + 255) / 256;
    const int nb  = (N + 1023) / 1024;   // 98 <= 128

    hipMemsetAsync(deg,  0, (size_t)N * 4, stream);
    hipMemsetAsync(cnt2, 0, (size_t)N * 4, stream);
    k_count<<<gE, 256, 0, stream>>>(dst, deg, E);
    k_dinv <<<gN, 256, 0, stream>>>(deg, dinv, N);
    k_scan1<<<nb, 1024, 0, stream>>>(deg, row_ptr, bsum, N);
    k_scan2<<<1, 128, 0, stream>>>(bsum, bexcl, nb);
    k_scan3<<<gN, 256, 0, stream>>>(row_ptr, bexcl, N, nb);
    k_fill <<<gE, 256, 0, stream>>>(src, dst, row_ptr, cnt2, col, E);

    k_gemm1<<<(N + 63) / 64, 256, 0, stream>>>(x, W1, dinv, h1s, N);
    k_agg1 <<<(N + 3) / 4, 256, 0, stream>>>(h1s, row_ptr, col, dinv, b1, out1, N);
    k_gemm2<<<(N + 127) / 128, 256, 0, stream>>>(out1, W2, dinv, h2s, N);
    k_agg2 <<<(N + 3) / 4, 256, 0, stream>>>(h2s, row_ptr, col, dinv, b2, out, N);
}

// Round 5
// 362.905 us; speedup vs baseline: 1.7137x; 1.0378x over previous
//
#include <hip/hip_runtime.h>
#include <hip/hip_fp16.h>

// GCN forward: 2x (GEMM + symmetric-normalized aggregation), fp32 in/out.
// CSR build via dst-bucketing (782 buckets of 128 nodes) to keep all scatter
// atomics/writes L2-local (kills the 16x partial-line write amplification).
// GEMM epilogues pre-scale rows by dinv[row] and store fp16 (internal only):
//   out[i] = d_i * (sum_{s in N(i)} h_s[s] + h_s[i]) + b
// Aggregations gather fp16 rows, accumulate fp32.

#define F_IN  128
#define F_H   128
#define F_OUT 40

#define BK_SHIFT 7          // 128 nodes per bucket
#define BK_MAX   1024       // max buckets supported (N <= 131072)
#define CHUNK    16384      // edges per block in bucketing kernels

// ---------------- bucketed CSR build ----------------

__global__ __launch_bounds__(256) void k_bhist(const int* __restrict__ dst,
                                               int* __restrict__ bcnt,
                                               int e, int nbk) {
    __shared__ int hist[BK_MAX];
    int e0 = blockIdx.x * CHUNK;
    int e1 = min(e0 + CHUNK, e);
    for (int i = threadIdx.x; i < nbk; i += 256) hist[i] = 0;
    __syncthreads();
    for (int i = e0 + threadIdx.x; i < e1; i += 256)
        atomicAdd(&hist[dst[i] >> BK_SHIFT], 1);
    __syncthreads();
    for (int i = threadIdx.x; i < nbk; i += 256) {
        int c = hist[i];
        if (c) atomicAdd(&bcnt[i], c);
    }
}

// one block: exclusive scan of bucket counts -> bucket write cursors
__global__ __launch_bounds__(1024) void k_bscan(const int* __restrict__ bcnt,
                                                int* __restrict__ bcur, int nbk) {
    __shared__ int s[1024];
    int v = (threadIdx.x < nbk) ? bcnt[threadIdx.x] : 0;
    s[threadIdx.x] = v;
    __syncthreads();
    for (int off = 1; off < 1024; off <<= 1) {
        int t = (threadIdx.x >= off) ? s[threadIdx.x - off] : 0;
        __syncthreads();
        s[threadIdx.x] += t;
        __syncthreads();
    }
    if (threadIdx.x < nbk) bcur[threadIdx.x] = s[threadIdx.x] - v;
}

// scatter (src,dst) into bucket-ordered ebuf; per-block contiguous runs
__global__ __launch_bounds__(256) void k_bscatter(const int* __restrict__ src,
                                                  const int* __restrict__ dst,
                                                  int* __restrict__ bcur,
                                                  int2* __restrict__ ebuf,
                                                  int e, int nbk) {
    __shared__ int hist[BK_MAX];
    __shared__ int base[BK_MAX];
    __shared__ int run[BK_MAX];
    int e0 = blockIdx.x * CHUNK;
    int e1 = min(e0 + CHUNK, e);
    for (int i = threadIdx.x; i < nbk; i += 256) { hist[i] = 0; run[i] = 0; }
    __syncthreads();
    for (int i = e0 + threadIdx.x; i < e1; i += 256)
        atomicAdd(&hist[dst[i] >> BK_SHIFT], 1);
    __syncthreads();
    for (int i = threadIdx.x; i < nbk; i += 256) {
        int c = hist[i];
        base[i] = c ? atomicAdd(&bcur[i], c) : 0;
    }
    __syncthreads();
    for (int i = e0 + threadIdx.x; i < e1; i += 256) {
        int d = dst[i];
        int b = d >> BK_SHIFT;
        int r = atomicAdd(&run[b], 1);
        ebuf[base[b] + r] = make_int2(src[i], d);
    }
}

// per-node degree from bucket-ordered edges (atomics confined to 512B windows)
__global__ void k_count2(const int2* __restrict__ ebuf, int* __restrict__ deg, int e) {
    int i = blockIdx.x * 256 + threadIdx.x;
    if (i < e) atomicAdd(&deg[ebuf[i].y], 1);
}

__global__ void k_dinv(const int* __restrict__ deg, float* __restrict__ dinv, int n) {
    int i = blockIdx.x * 256 + threadIdx.x;
    if (i < n) dinv[i] = rsqrtf((float)deg[i] + 1.0f);   // +1 self-loop
}

__global__ void k_scan1(const int* __restrict__ cnt, int* __restrict__ out,
                        int* __restrict__ bsum, int n) {
    __shared__ int s[1024];
    int i = blockIdx.x * 1024 + threadIdx.x;
    int v = (i < n) ? cnt[i] : 0;
    s[threadIdx.x] = v;
    __syncthreads();
    for (int off = 1; off < 1024; off <<= 1) {
        int t = (threadIdx.x >= off) ? s[threadIdx.x - off] : 0;
        __syncthreads();
        s[threadIdx.x] += t;
        __syncthreads();
    }
    if (i < n) out[i] = s[threadIdx.x] - v;
    if (threadIdx.x == 1023) bsum[blockIdx.x] = s[1023];
}

__global__ void k_scan2(const int* __restrict__ bsum, int* __restrict__ bexcl, int nb) {
    __shared__ int s[128];
    int v = (threadIdx.x < nb) ? bsum[threadIdx.x] : 0;
    s[threadIdx.x] = v;
    __syncthreads();
    for (int off = 1; off < 128; off <<= 1) {
        int t = (threadIdx.x >= off) ? s[threadIdx.x - off] : 0;
        __syncthreads();
        s[threadIdx.x] += t;
        __syncthreads();
    }
    if (threadIdx.x < nb) bexcl[threadIdx.x] = s[threadIdx.x] - v;
    if (threadIdx.x == 127) bexcl[nb] = s[127];
}

__global__ void k_scan3(int* __restrict__ out, const int* __restrict__ bexcl, int n, int nb) {
    int i = blockIdx.x * 256 + threadIdx.x;
    if (i < n) out[i] += bexcl[i >> 10];
    if (i == 0) out[n] = bexcl[nb];
}

// fill col from bucket-ordered edges: cnt2 atomics + col writes are L2-local
__global__ void k_fill2(const int2* __restrict__ ebuf,
                        const int* __restrict__ row_ptr, int* __restrict__ cnt2,
                        int* __restrict__ col, int e) {
    int i = blockIdx.x * 256 + threadIdx.x;
    if (i < e) {
        int2 ed = ebuf[i];
        int pos = row_ptr[ed.y] + atomicAdd(&cnt2[ed.y], 1);
        col[pos] = ed.x;
    }
}

// ---- GEMM 1: h1s = fp16( dinv .* (x @ W1) ), N x 128 @ 128 x 128 ----

__global__ __launch_bounds__(256) void k_gemm1(const float* __restrict__ x,
                                               const float* __restrict__ W,
                                               const float* __restrict__ dinv,
                                               __half* __restrict__ h, int n) {
    __shared__ float wsh[64 * 128];
    const int tid = threadIdx.x;
    const int c0  = (tid & 31) * 4;
    const int r0  = blockIdx.x * 64 + (tid >> 5) * 8;

    int xoff[8];
#pragma unroll
    for (int i = 0; i < 8; ++i) {
        int gr = r0 + i;
        if (gr > n - 1) gr = n - 1;
        xoff[i] = gr * F_IN;
    }

    float acc[8][4] = {};
#pragma unroll
    for (int half = 0; half < 2; ++half) {
        const int kb = half * 64;
        __syncthreads();
        for (int i = tid * 4; i < 64 * 128; i += 1024)
            *(float4*)&wsh[i] = *(const float4*)&W[kb * 128 + i];
        __syncthreads();

        float4 xa[8], xb[8];
#pragma unroll
        for (int i = 0; i < 8; ++i) xa[i] = *(const float4*)&x[xoff[i] + kb];

        for (int kk = 0; kk < 64; kk += 8) {
#pragma unroll
            for (int i = 0; i < 8; ++i) xb[i] = *(const float4*)&x[xoff[i] + kb + kk + 4];
#pragma unroll
            for (int k4 = 0; k4 < 4; ++k4) {
                float4 bv = *(const float4*)&wsh[(kk + k4) * 128 + c0];
#pragma unroll
                for (int i = 0; i < 8; ++i) {
                    float a = ((const float*)&xa[i])[k4];
                    acc[i][0] = fmaf(a, bv.x, acc[i][0]);
                    acc[i][1] = fmaf(a, bv.y, acc[i][1]);
                    acc[i][2] = fmaf(a, bv.z, acc[i][2]);
                    acc[i][3] = fmaf(a, bv.w, acc[i][3]);
                }
            }
            if (kk + 8 < 64) {
#pragma unroll
                for (int i = 0; i < 8; ++i) xa[i] = *(const float4*)&x[xoff[i] + kb + kk + 8];
            }
#pragma unroll
            for (int k4 = 0; k4 < 4; ++k4) {
                float4 bv = *(const float4*)&wsh[(kk + 4 + k4) * 128 + c0];
#pragma unroll
                for (int i = 0; i < 8; ++i) {
                    float a = ((const float*)&xb[i])[k4];
                    acc[i][0] = fmaf(a, bv.x, acc[i][0]);
                    acc[i][1] = fmaf(a, bv.y, acc[i][1]);
                    acc[i][2] = fmaf(a, bv.z, acc[i][2]);
                    acc[i][3] = fmaf(a, bv.w, acc[i][3]);
                }
            }
        }
    }

#pragma unroll
    for (int i = 0; i < 8; ++i) {
        int gr = r0 + i;
        if (gr < n) {
            float d = dinv[gr];
            __half2 p0 = __floats2half2_rn(acc[i][0] * d, acc[i][1] * d);
            __half2 p1 = __floats2half2_rn(acc[i][2] * d, acc[i][3] * d);
            uint2 pk;
            pk.x = *(unsigned int*)&p0;
            pk.y = *(unsigned int*)&p1;
            *(uint2*)&h[gr * F_H + c0] = pk;
        }
    }
}

// ---- Aggregation layer 1 (128 feats, fp16 rows): wave/node ----

__global__ __launch_bounds__(256) void k_agg1(const __half* __restrict__ h1s,
                                              const int* __restrict__ row_ptr,
                                              const int* __restrict__ col,
                                              const float* __restrict__ dinv,
                                              const float* __restrict__ b1,
                                              float* __restrict__ out1, int n) {
    int wid = (blockIdx.x * 256 + threadIdx.x) >> 6;
    int lane = threadIdx.x & 63;
    if (wid >= n) return;
    int beg = row_ptr[wid], end = row_ptr[wid + 1];
    const __half2* hb = (const __half2*)h1s + lane;   // row stride 64 half2

    float a0x = 0.f, a0y = 0.f, a1x = 0.f, a1y = 0.f;
    float a2x = 0.f, a2y = 0.f, a3x = 0.f, a3y = 0.f;
    int idx = beg;
    for (; idx + 8 <= end; idx += 8) {
        int s0 = col[idx],     s1 = col[idx + 1], s2 = col[idx + 2], s3 = col[idx + 3];
        int s4 = col[idx + 4], s5 = col[idx + 5], s6 = col[idx + 6], s7 = col[idx + 7];
        float2 v0 = __half22float2(hb[s0 << 6]);
        float2 v1 = __half22float2(hb[s1 << 6]);
        float2 v2 = __half22float2(hb[s2 << 6]);
        float2 v3 = __half22float2(hb[s3 << 6]);
        float2 v4 = __half22float2(hb[s4 << 6]);
        float2 v5 = __half22float2(hb[s5 << 6]);
        float2 v6 = __half22float2(hb[s6 << 6]);
        float2 v7 = __half22float2(hb[s7 << 6]);
        a0x += v0.x; a0y += v0.y; a1x += v1.x; a1y += v1.y;
        a2x += v2.x; a2y += v2.y; a3x += v3.x; a3y += v3.y;
        a0x += v4.x; a0y += v4.y; a1x += v5.x; a1y += v5.y;
        a2x += v6.x; a2y += v6.y; a3x += v7.x; a3y += v7.y;
    }
    if (idx + 4 <= end) {
        int s0 = col[idx], s1 = col[idx + 1], s2 = col[idx + 2], s3 = col[idx + 3];
        float2 v0 = __half22float2(hb[s0 << 6]);
        float2 v1 = __half22float2(hb[s1 << 6]);
        float2 v2 = __half22float2(hb[s2 << 6]);
        float2 v3 = __half22float2(hb[s3 << 6]);
        a0x += v0.x; a0y += v0.y; a1x += v1.x; a1y += v1.y;
        a2x += v2.x; a2y += v2.y; a3x += v3.x; a3y += v3.y;
        idx += 4;
    }
    for (; idx < end; ++idx) {
        float2 v = __half22float2(hb[col[idx] << 6]);
        a0x += v.x; a0y += v.y;
    }
    float2 hv = __half22float2(hb[wid << 6]);   // self (already dinv-scaled)
    float ax = (((a0x + a1x) + (a2x + a3x)) + hv.x);
    float ay = (((a0y + a1y) + (a2y + a3y)) + hv.y);
    float di = dinv[wid];
    int c2 = lane * 2;
    ax = fmaf(ax, di, b1[c2]);
    ay = fmaf(ay, di, b1[c2 + 1]);
    float2 o;
    o.x = fmaxf(ax, 0.f);
    o.y = fmaxf(ay, 0.f);
    *(float2*)&out1[(wid << 7) + c2] = o;
}

// ---- GEMM 2: h2s = fp16( dinv .* (out1 @ W2) ), N x 128 @ 128 x 40 ----

__global__ __launch_bounds__(256) void k_gemm2(const float* __restrict__ xin,
                                               const float* __restrict__ W,
                                               const float* __restrict__ dinv,
                                               __half* __restrict__ h, int n) {
    __shared__ float wsh[128 * F_OUT];
    const int tid = threadIdx.x;
    const int c0  = (tid & 7) * 5;
    const int r0  = blockIdx.x * 128 + (tid >> 3) * 4;

    for (int i = tid * 4; i < 128 * F_OUT; i += 1024)
        *(float4*)&wsh[i] = *(const float4*)&W[i];

    int xoff[4];
#pragma unroll
    for (int i = 0; i < 4; ++i) {
        int gr = r0 + i;
        if (gr > n - 1) gr = n - 1;
        xoff[i] = gr * F_H;
    }
    __syncthreads();

    float acc[4][5] = {};
    float4 xa[4], xb[4];
#pragma unroll
    for (int i = 0; i < 4; ++i) xa[i] = *(const float4*)&xin[xoff[i]];

    for (int kk = 0; kk < 128; kk += 8) {
#pragma unroll
        for (int i = 0; i < 4; ++i) xb[i] = *(const float4*)&xin[xoff[i] + kk + 4];
#pragma unroll
        for (int k4 = 0; k4 < 4; ++k4) {
            float bv[5];
#pragma unroll
            for (int j = 0; j < 5; ++j) bv[j] = wsh[(kk + k4) * F_OUT + c0 + j];
#pragma unroll
            for (int i = 0; i < 4; ++i) {
                float a = ((const float*)&xa[i])[k4];
#pragma unroll
                for (int j = 0; j < 5; ++j) acc[i][j] = fmaf(a, bv[j], acc[i][j]);
            }
        }
        if (kk + 8 < 128) {
#pragma unroll
            for (int i = 0; i < 4; ++i) xa[i] = *(const float4*)&xin[xoff[i] + kk + 8];
        }
#pragma unroll
        for (int k4 = 0; k4 < 4; ++k4) {
            float bv[5];
#pragma unroll
            for (int j = 0; j < 5; ++j) bv[j] = wsh[(kk + 4 + k4) * F_OUT + c0 + j];
#pragma unroll
            for (int i = 0; i < 4; ++i) {
                float a = ((const float*)&xb[i])[k4];
#pragma unroll
                for (int j = 0; j < 5; ++j) acc[i][j] = fmaf(a, bv[j], acc[i][j]);
            }
        }
    }

#pragma unroll
    for (int i = 0; i < 4; ++i) {
        int gr = r0 + i;
        if (gr < n) {
            float d = dinv[gr];
#pragma unroll
            for (int j = 0; j < 5; ++j)
                h[gr * F_OUT + c0 + j] = __float2half_rn(acc[i][j] * d);
        }
    }
}

// ---- Aggregation layer 2 (40 feats, fp16 rows): wave/node, 3 edges/slot ----

__global__ __launch_bounds__(256) void k_agg2(const __half* __restrict__ h2s,
                                              const int* __restrict__ row_ptr,
                                              const int* __restrict__ col,
                                              const float* __restrict__ dinv,
                                              const float* __restrict__ b2,
                                              float* __restrict__ out, int n) {
    int wid = (blockIdx.x * 256 + threadIdx.x) >> 6;
    int lane = threadIdx.x & 63;
    if (wid >= n) return;
    int third = lane / 20;
    bool act = (third < 3);
    int ll = act ? (lane - third * 20) : 0;
    const __half2* hb = (const __half2*)h2s + ll;
    int beg = row_ptr[wid], end = row_ptr[wid + 1];

    float a0x = 0.f, a0y = 0.f, a1x = 0.f, a1y = 0.f;
    float a2x = 0.f, a2y = 0.f, a3x = 0.f, a3y = 0.f;
    int idx = act ? (beg + third) : end;
    for (; idx + 9 < end; idx += 12) {
        int s0 = col[idx], s1 = col[idx + 3], s2 = col[idx + 6], s3 = col[idx + 9];
        float2 v0 = __half22float2(hb[s0 * 20]);
        float2 v1 = __half22float2(hb[s1 * 20]);
        float2 v2 = __half22float2(hb[s2 * 20]);
        float2 v3 = __half22float2(hb[s3 * 20]);
        a0x += v0.x; a0y += v0.y; a1x += v1.x; a1y += v1.y;
        a2x += v2.x; a2y += v2.y; a3x += v3.x; a3y += v3.y;
    }
    for (; idx < end; idx += 3) {
        float2 v = __half22float2(hb[col[idx] * 20]);
        a0x += v.x; a0y += v.y;
    }
    float tx = (a0x + a1x) + (a2x + a3x);
    float ty = (a0y + a1y) + (a2y + a3y);
    tx += __shfl(tx, lane + 20) + __shfl(tx, lane + 40);
    ty += __shfl(ty, lane + 20) + __shfl(ty, lane + 40);
    if (third == 0) {
        float2 hv = __half22float2(hb[wid * 20]);  // self
        float di = dinv[wid];
        int c2 = ll * 2;
        float2 o;
        o.x = fmaf(tx + hv.x, di, b2[c2]);
        o.y = fmaf(ty + hv.y, di, b2[c2 + 1]);
        *(float2*)&out[wid * F_OUT + c2] = o;
    }
}

// ---------------- launch ----------------

extern "C" void kernel_launch(void* const* d_in, const int* in_sizes, int n_in,
                              void* d_out, int out_size, void* d_ws, size_t ws_size,
                              hipStream_t stream) {
    const float* x  = (const float*)d_in[0];
    const int*   ei = (const int*)d_in[1];
    const float* W1 = (const float*)d_in[2];
    const float* b1 = (const float*)d_in[3];
    const float* W2 = (const float*)d_in[4];
    const float* b2 = (const float*)d_in[5];
    float* out = (float*)d_out;

    const int N = in_sizes[0] / F_IN;     // 100000
    const int E = in_sizes[1] / 2;        // 1600000
    const int* src = ei;
    const int* dst = ei + E;
    const int nbk = (N + (1 << BK_SHIFT) - 1) >> BK_SHIFT;   // 782

    char* ws = (char*)d_ws;
    size_t off = 0;
    auto alloc = [&](size_t bytes) -> void* {
        off = (off + 255) & ~(size_t)255;
        void* p = ws + off;
        off += bytes;
        return p;
    };
    int*    deg     = (int*)   alloc((size_t)N * 4);
    int*    cnt2    = (int*)   alloc((size_t)N * 4);
    float*  dinv    = (float*) alloc((size_t)N * 4);
    int*    row_ptr = (int*)   alloc((size_t)(N + 1) * 4);
    int*    bsum    = (int*)   alloc(129 * 4);
    int*    bexcl   = (int*)   alloc(129 * 4);
    int*    bcnt    = (int*)   alloc(BK_MAX * 4);
    int*    bcur    = (int*)   alloc(BK_MAX * 4);
    int2*   ebuf    = (int2*)  alloc((size_t)E * 8);
    int*    col     = (int*)   alloc((size_t)E * 4);
    __half* h1s     = (__half*)alloc((size_t)N * F_H * 2);
    float*  out1    = (float*) alloc((size_t)N * F_H * 4);
    __half* h2s     = h1s;     // h1s dead after k_agg1 -> reuse

    const int gN  = (N + 255) / 256;
    const int gE  = (E + 255) / 256;
    const int gC  = (E + CHUNK - 1) / CHUNK;   // 98
    const int nb  = (N + 1023) / 1024;         // 98 <= 128

    hipMemsetAsync(deg,  0, (size_t)N * 4, stream);
    hipMemsetAsync(cnt2, 0, (size_t)N * 4, stream);
    hipMemsetAsync(bcnt, 0, (size_t)nbk * 4, stream);

    k_bhist   <<<gC, 256, 0, stream>>>(dst, bcnt, E, nbk);
    k_bscan   <<<1, 1024, 0, stream>>>(bcnt, bcur, nbk);
    k_bscatter<<<gC, 256, 0, stream>>>(src, dst, bcur, ebuf, E, nbk);
    k_count2  <<<gE, 256, 0, stream>>>(ebuf, deg, E);
    k_dinv    <<<gN, 256, 0, stream>>>(deg, dinv, N);
    k_scan1   <<<nb, 1024, 0, stream>>>(deg, row_ptr, bsum, N);
    k_scan2   <<<1, 128, 0, stream>>>(bsum, bexcl, nb);
    k_scan3   <<<gN, 256, 0, stream>>>(row_ptr, bexcl, N, nb);
    k_fill2   <<<gE, 256, 0, stream>>>(ebuf, row_ptr, cnt2, col, E);

    k_gemm1<<<(N + 63) / 64, 256, 0, stream>>>(x, W1, dinv, h1s, N);
    k_agg1 <<<(N + 3) / 4, 256, 0, stream>>>(h1s, row_ptr, col, dinv, b1, out1, N);
    k_gemm2<<<(N + 127) / 128, 256, 0, stream>>>(out1, W2, dinv, h2s, N);
    k_agg2 <<<(N + 3) / 4, 256, 0, stream>>>(h2s, row_ptr, col, dinv, b2, out, N);
}

// Round 6
// 301.800 us; speedup vs baseline: 2.0606x; 1.2025x over previous
//
#include <hip/hip_runtime.h>
#include <hip/hip_fp16.h>

// GCN forward: 2x (MFMA fp16 GEMM + symmetric-normalized aggregation), fp32 in/out.
// CSR build via dst-bucketing (L2-local scatter).
// GEMMs use v_mfma_f32_16x16x32_f16; W pre-transposed to fp16 + XOR-swizzled
// into a global "LDS image" once, blocks linear-copy it to LDS.
// GEMM epilogues pre-scale rows by dinv[row], store fp16:
//   out[i] = d_i * (sum_{s in N(i)} h_s[s] + h_s[i]) + b

#define F_IN  128
#define F_H   128
#define F_OUT 40

#define BK_SHIFT 7
#define BK_MAX   1024
#define CHUNK    16384

typedef _Float16 half8v __attribute__((ext_vector_type(8)));
typedef float    f32x4  __attribute__((ext_vector_type(4)));

// ---------------- W prep: fp32 W[k][j] -> fp16 image[j][k ^ ((j&7)<<3)] ----------------

__global__ void k_prepW1(const float* __restrict__ W, __half* __restrict__ img) {
    int idx = blockIdx.x * 256 + threadIdx.x;   // 128*128
    int j = idx >> 7, k = idx & 127;
    img[j * 128 + (k ^ ((j & 7) << 3))] = __float2half_rn(W[k * 128 + j]);
}

__global__ void k_prepW2(const float* __restrict__ W, __half* __restrict__ img) {
    int idx = blockIdx.x * 256 + threadIdx.x;   // 48*128
    if (idx >= 48 * 128) return;
    int j = idx >> 7, k = idx & 127;
    float v = (j < F_OUT) ? W[k * F_OUT + j] : 0.f;
    img[j * 128 + (k ^ ((j & 7) << 3))] = __float2half_rn(v);
}

// ---------------- bucketed CSR build ----------------

__global__ __launch_bounds__(256) void k_bhist(const int* __restrict__ dst,
                                               int* __restrict__ bcnt,
                                               int e, int nbk) {
    __shared__ int hist[BK_MAX];
    int e0 = blockIdx.x * CHUNK;
    int e1 = min(e0 + CHUNK, e);
    for (int i = threadIdx.x; i < nbk; i += 256) hist[i] = 0;
    __syncthreads();
    for (int i = e0 + threadIdx.x; i < e1; i += 256)
        atomicAdd(&hist[dst[i] >> BK_SHIFT], 1);
    __syncthreads();
    for (int i = threadIdx.x; i < nbk; i += 256) {
        int c = hist[i];
        if (c) atomicAdd(&bcnt[i], c);
    }
}

__global__ __launch_bounds__(1024) void k_bscan(const int* __restrict__ bcnt,
                                                int* __restrict__ bcur, int nbk) {
    __shared__ int s[1024];
    int v = (threadIdx.x < nbk) ? bcnt[threadIdx.x] : 0;
    s[threadIdx.x] = v;
    __syncthreads();
    for (int off = 1; off < 1024; off <<= 1) {
        int t = (threadIdx.x >= off) ? s[threadIdx.x - off] : 0;
        __syncthreads();
        s[threadIdx.x] += t;
        __syncthreads();
    }
    if (threadIdx.x < nbk) bcur[threadIdx.x] = s[threadIdx.x] - v;
}

__global__ __launch_bounds__(256) void k_bscatter(const int* __restrict__ src,
                                                  const int* __restrict__ dst,
                                                  int* __restrict__ bcur,
                                                  int2* __restrict__ ebuf,
                                                  int e, int nbk) {
    __shared__ int hist[BK_MAX];
    __shared__ int base[BK_MAX];
    __shared__ int run[BK_MAX];
    int e0 = blockIdx.x * CHUNK;
    int e1 = min(e0 + CHUNK, e);
    for (int i = threadIdx.x; i < nbk; i += 256) { hist[i] = 0; run[i] = 0; }
    __syncthreads();
    for (int i = e0 + threadIdx.x; i < e1; i += 256)
        atomicAdd(&hist[dst[i] >> BK_SHIFT], 1);
    __syncthreads();
    for (int i = threadIdx.x; i < nbk; i += 256) {
        int c = hist[i];
        base[i] = c ? atomicAdd(&bcur[i], c) : 0;
    }
    __syncthreads();
    for (int i = e0 + threadIdx.x; i < e1; i += 256) {
        int d = dst[i];
        int b = d >> BK_SHIFT;
        int r = atomicAdd(&run[b], 1);
        ebuf[base[b] + r] = make_int2(src[i], d);
    }
}

__global__ void k_count2(const int2* __restrict__ ebuf, int* __restrict__ deg, int e) {
    int i = blockIdx.x * 256 + threadIdx.x;
    if (i < e) atomicAdd(&deg[ebuf[i].y], 1);
}

__global__ void k_dinv(const int* __restrict__ deg, float* __restrict__ dinv, int n) {
    int i = blockIdx.x * 256 + threadIdx.x;
    if (i < n) dinv[i] = rsqrtf((float)deg[i] + 1.0f);
}

__global__ void k_scan1(const int* __restrict__ cnt, int* __restrict__ out,
                        int* __restrict__ bsum, int n) {
    __shared__ int s[1024];
    int i = blockIdx.x * 1024 + threadIdx.x;
    int v = (i < n) ? cnt[i] : 0;
    s[threadIdx.x] = v;
    __syncthreads();
    for (int off = 1; off < 1024; off <<= 1) {
        int t = (threadIdx.x >= off) ? s[threadIdx.x - off] : 0;
        __syncthreads();
        s[threadIdx.x] += t;
        __syncthreads();
    }
    if (i < n) out[i] = s[threadIdx.x] - v;
    if (threadIdx.x == 1023) bsum[blockIdx.x] = s[1023];
}

__global__ void k_scan2(const int* __restrict__ bsum, int* __restrict__ bexcl, int nb) {
    __shared__ int s[128];
    int v = (threadIdx.x < nb) ? bsum[threadIdx.x] : 0;
    s[threadIdx.x] = v;
    __syncthreads();
    for (int off = 1; off < 128; off <<= 1) {
        int t = (threadIdx.x >= off) ? s[threadIdx.x - off] : 0;
        __syncthreads();
        s[threadIdx.x] += t;
        __syncthreads();
    }
    if (threadIdx.x < nb) bexcl[threadIdx.x] = s[threadIdx.x] - v;
    if (threadIdx.x == 127) bexcl[nb] = s[127];
}

__global__ void k_scan3(int* __restrict__ out, const int* __restrict__ bexcl, int n, int nb) {
    int i = blockIdx.x * 256 + threadIdx.x;
    if (i < n) out[i] += bexcl[i >> 10];
    if (i == 0) out[n] = bexcl[nb];
}

__global__ void k_fill2(const int2* __restrict__ ebuf,
                        const int* __restrict__ row_ptr, int* __restrict__ cnt2,
                        int* __restrict__ col, int e) {
    int i = blockIdx.x * 256 + threadIdx.x;
    if (i < e) {
        int2 ed = ebuf[i];
        int pos = row_ptr[ed.y] + atomicAdd(&cnt2[ed.y], 1);
        col[pos] = ed.x;
    }
}

// ---- GEMM 1 (MFMA): h1s = fp16( dinv .* (x @ W1) ), A fp32->fp16 stream ----
// block = 4 waves x 16 rows = 64 rows; full N=128 (8 col-tiles), K=128 (4 steps).
// A: lane&15 = row, k = (lane>>4)*8+i. B from swizzled LDS image. D: row=(lane>>4)*4+b.

__global__ __launch_bounds__(256) void k_gemm1(const float* __restrict__ x,
                                               const __half* __restrict__ Wimg,
                                               const float* __restrict__ dinv,
                                               __half* __restrict__ h, int n) {
    __shared__ __half wlds[128 * 128];   // 32 KB swizzled W1^T image
    const int tid = threadIdx.x;
#pragma unroll
    for (int it = 0; it < 8; ++it) {
        int i = tid * 8 + it * 2048;
        *(uint4*)&wlds[i] = *(const uint4*)&Wimg[i];
    }

    const int l  = tid & 63;
    const int g  = l >> 4;
    const int r0 = blockIdx.x * 64 + (tid >> 6) * 16;
    int row = r0 + (l & 15);
    if (row > n - 1) row = n - 1;

    const float* xb = x + row * F_IN + g * 8;
    half8v afr[4];
#pragma unroll
    for (int kk = 0; kk < 4; ++kk) {
        float4 u0 = *(const float4*)(xb + kk * 32);
        float4 u1 = *(const float4*)(xb + kk * 32 + 4);
        half8v a;
        a[0] = (_Float16)u0.x; a[1] = (_Float16)u0.y;
        a[2] = (_Float16)u0.z; a[3] = (_Float16)u0.w;
        a[4] = (_Float16)u1.x; a[5] = (_Float16)u1.y;
        a[6] = (_Float16)u1.z; a[7] = (_Float16)u1.w;
        afr[kk] = a;
    }
    __syncthreads();

    const char* wb = (const char*)wlds;
    const int swz = (l & 7) << 4;
    f32x4 acc[8] = {};
#pragma unroll
    for (int ct = 0; ct < 8; ++ct) {
        const int base = (ct * 16 + (l & 15)) * 256;
#pragma unroll
        for (int kk = 0; kk < 4; ++kk) {
            half8v bfr = *(const half8v*)(wb + base + ((kk * 64 + g * 16) ^ swz));
            acc[ct] = __builtin_amdgcn_mfma_f32_16x16x32_f16(afr[kk], bfr, acc[ct], 0, 0, 0);
        }
    }

    const int orow0 = r0 + g * 4;
    float dv[4];
#pragma unroll
    for (int b = 0; b < 4; ++b) {
        int r = orow0 + b;
        dv[b] = (r < n) ? dinv[r] : 0.f;
    }
#pragma unroll
    for (int ct = 0; ct < 8; ++ct) {
#pragma unroll
        for (int b = 0; b < 4; ++b) {
            int r = orow0 + b;
            if (r < n)
                h[r * F_H + ct * 16 + (l & 15)] = __float2half_rn(acc[ct][b] * dv[b]);
        }
    }
}

// ---- Aggregation layer 1 (128 feats, fp16 rows): wave/node, fp16 out ----

__global__ __launch_bounds__(256) void k_agg1(const __half* __restrict__ h1s,
                                              const int* __restrict__ row_ptr,
                                              const int* __restrict__ col,
                                              const float* __restrict__ dinv,
                                              const float* __restrict__ b1,
                                              __half* __restrict__ out1, int n) {
    int wid = (blockIdx.x * 256 + threadIdx.x) >> 6;
    int lane = threadIdx.x & 63;
    if (wid >= n) return;
    int beg = row_ptr[wid], end = row_ptr[wid + 1];
    const __half2* hb = (const __half2*)h1s + lane;

    float a0x = 0.f, a0y = 0.f, a1x = 0.f, a1y = 0.f;
    float a2x = 0.f, a2y = 0.f, a3x = 0.f, a3y = 0.f;
    int idx = beg;
    for (; idx + 8 <= end; idx += 8) {
        int s0 = col[idx],     s1 = col[idx + 1], s2 = col[idx + 2], s3 = col[idx + 3];
        int s4 = col[idx + 4], s5 = col[idx + 5], s6 = col[idx + 6], s7 = col[idx + 7];
        float2 v0 = __half22float2(hb[s0 << 6]);
        float2 v1 = __half22float2(hb[s1 << 6]);
        float2 v2 = __half22float2(hb[s2 << 6]);
        float2 v3 = __half22float2(hb[s3 << 6]);
        float2 v4 = __half22float2(hb[s4 << 6]);
        float2 v5 = __half22float2(hb[s5 << 6]);
        float2 v6 = __half22float2(hb[s6 << 6]);
        float2 v7 = __half22float2(hb[s7 << 6]);
        a0x += v0.x; a0y += v0.y; a1x += v1.x; a1y += v1.y;
        a2x += v2.x; a2y += v2.y; a3x += v3.x; a3y += v3.y;
        a0x += v4.x; a0y += v4.y; a1x += v5.x; a1y += v5.y;
        a2x += v6.x; a2y += v6.y; a3x += v7.x; a3y += v7.y;
    }
    if (idx + 4 <= end) {
        int s0 = col[idx], s1 = col[idx + 1], s2 = col[idx + 2], s3 = col[idx + 3];
        float2 v0 = __half22float2(hb[s0 << 6]);
        float2 v1 = __half22float2(hb[s1 << 6]);
        float2 v2 = __half22float2(hb[s2 << 6]);
        float2 v3 = __half22float2(hb[s3 << 6]);
        a0x += v0.x; a0y += v0.y; a1x += v1.x; a1y += v1.y;
        a2x += v2.x; a2y += v2.y; a3x += v3.x; a3y += v3.y;
        idx += 4;
    }
    for (; idx < end; ++idx) {
        float2 v = __half22float2(hb[col[idx] << 6]);
        a0x += v.x; a0y += v.y;
    }
    float2 hv = __half22float2(hb[wid << 6]);
    float ax = (((a0x + a1x) + (a2x + a3x)) + hv.x);
    float ay = (((a0y + a1y) + (a2y + a3y)) + hv.y);
    float di = dinv[wid];
    int c2 = lane * 2;
    ax = fmaf(ax, di, b1[c2]);
    ay = fmaf(ay, di, b1[c2 + 1]);
    __half2 o = __floats2half2_rn(fmaxf(ax, 0.f), fmaxf(ay, 0.f));
    *(__half2*)&out1[(wid << 7) + c2] = o;
}

// ---- GEMM 2 (MFMA): h2s = fp16( dinv .* (out1 @ W2) ), A fp16 stream ----
// N padded to 48 (3 col-tiles); stores guarded to col<40.

__global__ __launch_bounds__(256) void k_gemm2(const __half* __restrict__ xin,
                                               const __half* __restrict__ Wimg,
                                               const float* __restrict__ dinv,
                                               __half* __restrict__ h, int n) {
    __shared__ __half wlds[48 * 128];   // 12 KB swizzled W2^T image
    const int tid = threadIdx.x;
#pragma unroll
    for (int it = 0; it < 3; ++it) {
        int i = tid * 8 + it * 2048;
        *(uint4*)&wlds[i] = *(const uint4*)&Wimg[i];
    }

    const int l  = tid & 63;
    const int g  = l >> 4;
    const int r0 = blockIdx.x * 64 + (tid >> 6) * 16;
    int row = r0 + (l & 15);
    if (row > n - 1) row = n - 1;

    const __half* ab = xin + row * F_H + g * 8;
    half8v afr[4];
#pragma unroll
    for (int kk = 0; kk < 4; ++kk) afr[kk] = *(const half8v*)(ab + kk * 32);
    __syncthreads();

    const char* wb = (const char*)wlds;
    const int swz = (l & 7) << 4;
    f32x4 acc[3] = {};
#pragma unroll
    for (int ct = 0; ct < 3; ++ct) {
        const int base = (ct * 16 + (l & 15)) * 256;
#pragma unroll
        for (int kk = 0; kk < 4; ++kk) {
            half8v bfr = *(const half8v*)(wb + base + ((kk * 64 + g * 16) ^ swz));
            acc[ct] = __builtin_amdgcn_mfma_f32_16x16x32_f16(afr[kk], bfr, acc[ct], 0, 0, 0);
        }
    }

    const int orow0 = r0 + g * 4;
    float dv[4];
#pragma unroll
    for (int b = 0; b < 4; ++b) {
        int r = orow0 + b;
        dv[b] = (r < n) ? dinv[r] : 0.f;
    }
#pragma unroll
    for (int ct = 0; ct < 3; ++ct) {
        int c = ct * 16 + (l & 15);
#pragma unroll
        for (int b = 0; b < 4; ++b) {
            int r = orow0 + b;
            if (r < n && c < F_OUT)
                h[r * F_OUT + c] = __float2half_rn(acc[ct][b] * dv[b]);
        }
    }
}

// ---- Aggregation layer 2 (40 feats, fp16 rows): wave/node, 3 edges/slot ----

__global__ __launch_bounds__(256) void k_agg2(const __half* __restrict__ h2s,
                                              const int* __restrict__ row_ptr,
                                              const int* __restrict__ col,
                                              const float* __restrict__ dinv,
                                              const float* __restrict__ b2,
                                              float* __restrict__ out, int n) {
    int wid = (blockIdx.x * 256 + threadIdx.x) >> 6;
    int lane = threadIdx.x & 63;
    if (wid >= n) return;
    int third = lane / 20;
    bool act = (third < 3);
    int ll = act ? (lane - third * 20) : 0;
    const __half2* hb = (const __half2*)h2s + ll;
    int beg = row_ptr[wid], end = row_ptr[wid + 1];

    float a0x = 0.f, a0y = 0.f, a1x = 0.f, a1y = 0.f;
    float a2x = 0.f, a2y = 0.f, a3x = 0.f, a3y = 0.f;
    int idx = act ? (beg + third) : end;
    for (; idx + 9 < end; idx += 12) {
        int s0 = col[idx], s1 = col[idx + 3], s2 = col[idx + 6], s3 = col[idx + 9];
        float2 v0 = __half22float2(hb[s0 * 20]);
        float2 v1 = __half22float2(hb[s1 * 20]);
        float2 v2 = __half22float2(hb[s2 * 20]);
        float2 v3 = __half22float2(hb[s3 * 20]);
        a0x += v0.x; a0y += v0.y; a1x += v1.x; a1y += v1.y;
        a2x += v2.x; a2y += v2.y; a3x += v3.x; a3y += v3.y;
    }
    for (; idx < end; idx += 3) {
        float2 v = __half22float2(hb[col[idx] * 20]);
        a0x += v.x; a0y += v.y;
    }
    float tx = (a0x + a1x) + (a2x + a3x);
    float ty = (a0y + a1y) + (a2y + a3y);
    tx += __shfl(tx, lane + 20) + __shfl(tx, lane + 40);
    ty += __shfl(ty, lane + 20) + __shfl(ty, lane + 40);
    if (third == 0) {
        float2 hv = __half22float2(hb[wid * 20]);
        float di = dinv[wid];
        int c2 = ll * 2;
        float2 o;
        o.x = fmaf(tx + hv.x, di, b2[c2]);
        o.y = fmaf(ty + hv.y, di, b2[c2 + 1]);
        *(float2*)&out[wid * F_OUT + c2] = o;
    }
}

// ---------------- launch ----------------

extern "C" void kernel_launch(void* const* d_in, const int* in_sizes, int n_in,
                              void* d_out, int out_size, void* d_ws, size_t ws_size,
                              hipStream_t stream) {
    const float* x  = (const float*)d_in[0];
    const int*   ei = (const int*)d_in[1];
    const float* W1 = (const float*)d_in[2];
    const float* b1 = (const float*)d_in[3];
    const float* W2 = (const float*)d_in[4];
    const float* b2 = (const float*)d_in[5];
    float* out = (float*)d_out;

    const int N = in_sizes[0] / F_IN;     // 100000
    const int E = in_sizes[1] / 2;        // 1600000
    const int* src = ei;
    const int* dst = ei + E;
    const int nbk = (N + (1 << BK_SHIFT) - 1) >> BK_SHIFT;   // 782

    char* ws = (char*)d_ws;
    size_t off = 0;
    auto alloc = [&](size_t bytes) -> void* {
        off = (off + 255) & ~(size_t)255;
        void* p = ws + off;
        off += bytes;
        return p;
    };
    int*    deg     = (int*)   alloc((size_t)N * 4);
    int*    cnt2    = (int*)   alloc((size_t)N * 4);
    float*  dinv    = (float*) alloc((size_t)N * 4);
    int*    row_ptr = (int*)   alloc((size_t)(N + 1) * 4);
    int*    bsum    = (int*)   alloc(129 * 4);
    int*    bexcl   = (int*)   alloc(129 * 4);
    int*    bcnt    = (int*)   alloc(BK_MAX * 4);
    int*    bcur    = (int*)   alloc(BK_MAX * 4);
    __half* W1img   = (__half*)alloc(128 * 128 * 2);
    __half* W2img   = (__half*)alloc(48 * 128 * 2);
    int2*   ebuf    = (int2*)  alloc((size_t)E * 8);
    int*    col     = (int*)   alloc((size_t)E * 4);
    __half* h1s     = (__half*)alloc((size_t)N * F_H * 2);
    __half* out1h   = (__half*)alloc((size_t)N * F_H * 2);
    __half* h2s     = h1s;     // h1s dead after k_agg1 -> reuse

    const int gN  = (N + 255) / 256;
    const int gE  = (E + 255) / 256;
    const int gC  = (E + CHUNK - 1) / CHUNK;
    const int nb  = (N + 1023) / 1024;

    hipMemsetAsync(deg,  0, (size_t)N * 4, stream);
    hipMemsetAsync(cnt2, 0, (size_t)N * 4, stream);
    hipMemsetAsync(bcnt, 0, (size_t)nbk * 4, stream);

    k_prepW1  <<<64, 256, 0, stream>>>(W1, W1img);
    k_prepW2  <<<24, 256, 0, stream>>>(W2, W2img);

    k_bhist   <<<gC, 256, 0, stream>>>(dst, bcnt, E, nbk);
    k_bscan   <<<1, 1024, 0, stream>>>(bcnt, bcur, nbk);
    k_bscatter<<<gC, 256, 0, stream>>>(src, dst, bcur, ebuf, E, nbk);
    k_count2  <<<gE, 256, 0, stream>>>(ebuf, deg, E);
    k_dinv    <<<gN, 256, 0, stream>>>(deg, dinv, N);
    k_scan1   <<<nb, 1024, 0, stream>>>(deg, row_ptr, bsum, N);
    k_scan2   <<<1, 128, 0, stream>>>(bsum, bexcl, nb);
    k_scan3   <<<gN, 256, 0, stream>>>(row_ptr, bexcl, N, nb);
    k_fill2   <<<gE, 256, 0, stream>>>(ebuf, row_ptr, cnt2, col, E);

    k_gemm1<<<(N + 63) / 64, 256, 0, stream>>>(x, W1img, dinv, h1s, N);
    k_agg1 <<<(N + 3) / 4, 256, 0, stream>>>(h1s, row_ptr, col, dinv, b1, out1h, N);
    k_gemm2<<<(N + 63) / 64, 256, 0, stream>>>(out1h, W2img, dinv, h2s, N);
    k_agg2 <<<(N + 3) / 4, 256, 0, stream>>>(h2s, row_ptr, col, dinv, b2, out, N);
}

// Round 7
// 211.868 us; speedup vs baseline: 2.9353x; 1.4245x over previous
//
#include <hip/hip_runtime.h>
#include <hip/hip_fp16.h>

// GCN forward: 2x (MFMA fp16 GEMM + symmetric-normalized aggregation), fp32 in/out.
// CSR build: bucket edges by dst>>7 (4B packed (src<<7)|local), then ONE per-bucket
// kernel derives row_ptr (bucket_base + local scan), dinv, and fills col —
// no global N-scan, no node-level global atomics.
// GEMM epilogues pre-scale rows by dinv[row], store fp16:
//   out[i] = d_i * (sum_{s in N(i)} h_s[s] + h_s[i]) + b

#define F_IN  128
#define F_H   128
#define F_OUT 40

#define BK_SHIFT 7          // 128 nodes per bucket
#define BK_MAX   1024       // supports N <= 131072 (also src < 2^25 for packing)
#define CHUNK    4096       // edges per block in bucketing kernels

typedef _Float16 half8v __attribute__((ext_vector_type(8)));
typedef float    f32x4  __attribute__((ext_vector_type(4)));

// ---------------- W prep: fp32 W[k][j] -> fp16 image[j][k ^ ((j&7)<<3)] ----------------

__global__ void k_prepW1(const float* __restrict__ W, __half* __restrict__ img) {
    int idx = blockIdx.x * 256 + threadIdx.x;   // 128*128
    int j = idx >> 7, k = idx & 127;
    img[j * 128 + (k ^ ((j & 7) << 3))] = __float2half_rn(W[k * 128 + j]);
}

__global__ void k_prepW2(const float* __restrict__ W, __half* __restrict__ img) {
    int idx = blockIdx.x * 256 + threadIdx.x;   // 48*128
    if (idx >= 48 * 128) return;
    int j = idx >> 7, k = idx & 127;
    float v = (j < F_OUT) ? W[k * F_OUT + j] : 0.f;
    img[j * 128 + (k ^ ((j & 7) << 3))] = __float2half_rn(v);
}

// ---------------- bucketed CSR build ----------------

__global__ __launch_bounds__(256) void k_bhist(const int* __restrict__ dst,
                                               int* __restrict__ bcnt,
                                               int e, int nbk) {
    __shared__ int hist[BK_MAX];
    int e0 = blockIdx.x * CHUNK;
    int e1 = min(e0 + CHUNK, e);
    for (int i = threadIdx.x; i < nbk; i += 256) hist[i] = 0;
    __syncthreads();
    for (int i = e0 + threadIdx.x; i < e1; i += 256)
        atomicAdd(&hist[dst[i] >> BK_SHIFT], 1);
    __syncthreads();
    for (int i = threadIdx.x; i < nbk; i += 256) {
        int c = hist[i];
        if (c) atomicAdd(&bcnt[i], c);
    }
}

// one block: exclusive scan of bucket counts -> bbase[0..nbk] and bcur
__global__ __launch_bounds__(1024) void k_bscan(const int* __restrict__ bcnt,
                                                int* __restrict__ bbase,
                                                int* __restrict__ bcur, int nbk) {
    __shared__ int s[1024];
    int v = (threadIdx.x < nbk) ? bcnt[threadIdx.x] : 0;
    s[threadIdx.x] = v;
    __syncthreads();
    for (int off = 1; off < 1024; off <<= 1) {
        int t = (threadIdx.x >= off) ? s[threadIdx.x - off] : 0;
        __syncthreads();
        s[threadIdx.x] += t;
        __syncthreads();
    }
    if (threadIdx.x < nbk) {
        int excl = s[threadIdx.x] - v;
        bbase[threadIdx.x] = excl;
        bcur[threadIdx.x]  = excl;
        if (threadIdx.x == nbk - 1) bbase[nbk] = s[threadIdx.x];
    }
}

// scatter packed (src<<7 | dst&127) into bucket-ordered ebuf
__global__ __launch_bounds__(256) void k_bscatter(const int* __restrict__ src,
                                                  const int* __restrict__ dst,
                                                  int* __restrict__ bcur,
                                                  int* __restrict__ ebuf,
                                                  int e, int nbk) {
    __shared__ int hist[BK_MAX];
    __shared__ int base[BK_MAX];
    __shared__ int run[BK_MAX];
    int e0 = blockIdx.x * CHUNK;
    int e1 = min(e0 + CHUNK, e);
    for (int i = threadIdx.x; i < nbk; i += 256) { hist[i] = 0; run[i] = 0; }
    __syncthreads();
    for (int i = e0 + threadIdx.x; i < e1; i += 256)
        atomicAdd(&hist[dst[i] >> BK_SHIFT], 1);
    __syncthreads();
    for (int i = threadIdx.x; i < nbk; i += 256) {
        int c = hist[i];
        base[i] = c ? atomicAdd(&bcur[i], c) : 0;
    }
    __syncthreads();
    for (int i = e0 + threadIdx.x; i < e1; i += 256) {
        int d = dst[i];
        int b = d >> BK_SHIFT;
        int r = atomicAdd(&run[b], 1);
        ebuf[base[b] + r] = (src[i] << BK_SHIFT) | (d & ((1 << BK_SHIFT) - 1));
    }
}

// per-bucket: local hist -> row_ptr/dinv (coalesced), local cursors -> col fill.
__global__ __launch_bounds__(256) void k_bnode(const int* __restrict__ ebuf,
                                               const int* __restrict__ bbase,
                                               int* __restrict__ row_ptr,
                                               float* __restrict__ dinv,
                                               int* __restrict__ col,
                                               int n, int nbk) {
    __shared__ int hist[128];
    __shared__ int sc[128];
    __shared__ int cur[128];
    const int b   = blockIdx.x;
    const int tid = threadIdx.x;
    const int e0 = bbase[b], e1 = bbase[b + 1];

    if (tid < 128) hist[tid] = 0;
    __syncthreads();
    for (int i = e0 + tid; i < e1; i += 256)
        atomicAdd(&hist[ebuf[i] & 127], 1);
    __syncthreads();
    // exclusive scan of 128 counts (Hillis-Steele; all threads hit barriers)
    if (tid < 128) sc[tid] = hist[tid];
    __syncthreads();
    for (int off = 1; off < 128; off <<= 1) {
        int t = 0;
        if (tid < 128 && tid >= off) t = sc[tid - off];
        __syncthreads();
        if (tid < 128) sc[tid] += t;
        __syncthreads();
    }
    if (tid < 128) {
        int node = (b << BK_SHIFT) + tid;
        int excl = sc[tid] - hist[tid];
        if (node < n) {
            row_ptr[node] = e0 + excl;
            dinv[node] = rsqrtf((float)hist[tid] + 1.0f);   // +1 self-loop
        }
        cur[tid] = e0 + excl;
        if (b == nbk - 1 && tid == 0) row_ptr[n] = e1;
    }
    __syncthreads();
    for (int i = e0 + tid; i < e1; i += 256) {
        int w = ebuf[i];
        int pos = atomicAdd(&cur[w & 127], 1);
        col[pos] = w >> BK_SHIFT;
    }
}

// ---- GEMM 1 (MFMA): h1s = fp16( dinv .* (x @ W1) ) ----

__global__ __launch_bounds__(256) void k_gemm1(const float* __restrict__ x,
                                               const __half* __restrict__ Wimg,
                                               const float* __restrict__ dinv,
                                               __half* __restrict__ h, int n) {
    __shared__ __half wlds[128 * 128];
    const int tid = threadIdx.x;
#pragma unroll
    for (int it = 0; it < 8; ++it) {
        int i = tid * 8 + it * 2048;
        *(uint4*)&wlds[i] = *(const uint4*)&Wimg[i];
    }

    const int l  = tid & 63;
    const int g  = l >> 4;
    const int r0 = blockIdx.x * 64 + (tid >> 6) * 16;
    int row = r0 + (l & 15);
    if (row > n - 1) row = n - 1;

    const float* xb = x + row * F_IN + g * 8;
    half8v afr[4];
#pragma unroll
    for (int kk = 0; kk < 4; ++kk) {
        float4 u0 = *(const float4*)(xb + kk * 32);
        float4 u1 = *(const float4*)(xb + kk * 32 + 4);
        half8v a;
        a[0] = (_Float16)u0.x; a[1] = (_Float16)u0.y;
        a[2] = (_Float16)u0.z; a[3] = (_Float16)u0.w;
        a[4] = (_Float16)u1.x; a[5] = (_Float16)u1.y;
        a[6] = (_Float16)u1.z; a[7] = (_Float16)u1.w;
        afr[kk] = a;
    }
    __syncthreads();

    const char* wb = (const char*)wlds;
    const int swz = (l & 7) << 4;
    f32x4 acc[8] = {};
#pragma unroll
    for (int ct = 0; ct < 8; ++ct) {
        const int base = (ct * 16 + (l & 15)) * 256;
#pragma unroll
        for (int kk = 0; kk < 4; ++kk) {
            half8v bfr = *(const half8v*)(wb + base + ((kk * 64 + g * 16) ^ swz));
            acc[ct] = __builtin_amdgcn_mfma_f32_16x16x32_f16(afr[kk], bfr, acc[ct], 0, 0, 0);
        }
    }

    const int orow0 = r0 + g * 4;
    float dv[4];
#pragma unroll
    for (int b = 0; b < 4; ++b) {
        int r = orow0 + b;
        dv[b] = (r < n) ? dinv[r] : 0.f;
    }
#pragma unroll
    for (int ct = 0; ct < 8; ++ct) {
#pragma unroll
        for (int b = 0; b < 4; ++b) {
            int r = orow0 + b;
            if (r < n)
                h[r * F_H + ct * 16 + (l & 15)] = __float2half_rn(acc[ct][b] * dv[b]);
        }
    }
}

// ---- Aggregation layer 1 (128 feats, fp16 rows): wave/node, fp16 out ----

__global__ __launch_bounds__(256) void k_agg1(const __half* __restrict__ h1s,
                                              const int* __restrict__ row_ptr,
                                              const int* __restrict__ col,
                                              const float* __restrict__ dinv,
                                              const float* __restrict__ b1,
                                              __half* __restrict__ out1, int n) {
    int wid = (blockIdx.x * 256 + threadIdx.x) >> 6;
    int lane = threadIdx.x & 63;
    if (wid >= n) return;
    int beg = row_ptr[wid], end = row_ptr[wid + 1];
    const __half2* hb = (const __half2*)h1s + lane;

    float a0x = 0.f, a0y = 0.f, a1x = 0.f, a1y = 0.f;
    float a2x = 0.f, a2y = 0.f, a3x = 0.f, a3y = 0.f;
    int idx = beg;
    for (; idx + 8 <= end; idx += 8) {
        int s0 = col[idx],     s1 = col[idx + 1], s2 = col[idx + 2], s3 = col[idx + 3];
        int s4 = col[idx + 4], s5 = col[idx + 5], s6 = col[idx + 6], s7 = col[idx + 7];
        float2 v0 = __half22float2(hb[s0 << 6]);
        float2 v1 = __half22float2(hb[s1 << 6]);
        float2 v2 = __half22float2(hb[s2 << 6]);
        float2 v3 = __half22float2(hb[s3 << 6]);
        float2 v4 = __half22float2(hb[s4 << 6]);
        float2 v5 = __half22float2(hb[s5 << 6]);
        float2 v6 = __half22float2(hb[s6 << 6]);
        float2 v7 = __half22float2(hb[s7 << 6]);
        a0x += v0.x; a0y += v0.y; a1x += v1.x; a1y += v1.y;
        a2x += v2.x; a2y += v2.y; a3x += v3.x; a3y += v3.y;
        a0x += v4.x; a0y += v4.y; a1x += v5.x; a1y += v5.y;
        a2x += v6.x; a2y += v6.y; a3x += v7.x; a3y += v7.y;
    }
    if (idx + 4 <= end) {
        int s0 = col[idx], s1 = col[idx + 1], s2 = col[idx + 2], s3 = col[idx + 3];
        float2 v0 = __half22float2(hb[s0 << 6]);
        float2 v1 = __half22float2(hb[s1 << 6]);
        float2 v2 = __half22float2(hb[s2 << 6]);
        float2 v3 = __half22float2(hb[s3 << 6]);
        a0x += v0.x; a0y += v0.y; a1x += v1.x; a1y += v1.y;
        a2x += v2.x; a2y += v2.y; a3x += v3.x; a3y += v3.y;
        idx += 4;
    }
    for (; idx < end; ++idx) {
        float2 v = __half22float2(hb[col[idx] << 6]);
        a0x += v.x; a0y += v.y;
    }
    float2 hv = __half22float2(hb[wid << 6]);
    float ax = (((a0x + a1x) + (a2x + a3x)) + hv.x);
    float ay = (((a0y + a1y) + (a2y + a3y)) + hv.y);
    float di = dinv[wid];
    int c2 = lane * 2;
    ax = fmaf(ax, di, b1[c2]);
    ay = fmaf(ay, di, b1[c2 + 1]);
    __half2 o = __floats2half2_rn(fmaxf(ax, 0.f), fmaxf(ay, 0.f));
    *(__half2*)&out1[(wid << 7) + c2] = o;
}

// ---- GEMM 2 (MFMA): h2s = fp16( dinv .* (out1 @ W2) ) ----

__global__ __launch_bounds__(256) void k_gemm2(const __half* __restrict__ xin,
                                               const __half* __restrict__ Wimg,
                                               const float* __restrict__ dinv,
                                               __half* __restrict__ h, int n) {
    __shared__ __half wlds[48 * 128];
    const int tid = threadIdx.x;
#pragma unroll
    for (int it = 0; it < 3; ++it) {
        int i = tid * 8 + it * 2048;
        *(uint4*)&wlds[i] = *(const uint4*)&Wimg[i];
    }

    const int l  = tid & 63;
    const int g  = l >> 4;
    const int r0 = blockIdx.x * 64 + (tid >> 6) * 16;
    int row = r0 + (l & 15);
    if (row > n - 1) row = n - 1;

    const __half* ab = xin + row * F_H + g * 8;
    half8v afr[4];
#pragma unroll
    for (int kk = 0; kk < 4; ++kk) afr[kk] = *(const half8v*)(ab + kk * 32);
    __syncthreads();

    const char* wb = (const char*)wlds;
    const int swz = (l & 7) << 4;
    f32x4 acc[3] = {};
#pragma unroll
    for (int ct = 0; ct < 3; ++ct) {
        const int base = (ct * 16 + (l & 15)) * 256;
#pragma unroll
        for (int kk = 0; kk < 4; ++kk) {
            half8v bfr = *(const half8v*)(wb + base + ((kk * 64 + g * 16) ^ swz));
            acc[ct] = __builtin_amdgcn_mfma_f32_16x16x32_f16(afr[kk], bfr, acc[ct], 0, 0, 0);
        }
    }

    const int orow0 = r0 + g * 4;
    float dv[4];
#pragma unroll
    for (int b = 0; b < 4; ++b) {
        int r = orow0 + b;
        dv[b] = (r < n) ? dinv[r] : 0.f;
    }
#pragma unroll
    for (int ct = 0; ct < 3; ++ct) {
        int c = ct * 16 + (l & 15);
#pragma unroll
        for (int b = 0; b < 4; ++b) {
            int r = orow0 + b;
            if (r < n && c < F_OUT)
                h[r * F_OUT + c] = __float2half_rn(acc[ct][b] * dv[b]);
        }
    }
}

// ---- Aggregation layer 2 (40 feats, fp16 rows): wave/node, 3 edges/slot ----

__global__ __launch_bounds__(256) void k_agg2(const __half* __restrict__ h2s,
                                              const int* __restrict__ row_ptr,
                                              const int* __restrict__ col,
                                              const float* __restrict__ dinv,
                                              const float* __restrict__ b2,
                                              float* __restrict__ out, int n) {
    int wid = (blockIdx.x * 256 + threadIdx.x) >> 6;
    int lane = threadIdx.x & 63;
    if (wid >= n) return;
    int third = lane / 20;
    bool act = (third < 3);
    int ll = act ? (lane - third * 20) : 0;
    const __half2* hb = (const __half2*)h2s + ll;
    int beg = row_ptr[wid], end = row_ptr[wid + 1];

    float a0x = 0.f, a0y = 0.f, a1x = 0.f, a1y = 0.f;
    float a2x = 0.f, a2y = 0.f, a3x = 0.f, a3y = 0.f;
    int idx = act ? (beg + third) : end;
    for (; idx + 9 < end; idx += 12) {
        int s0 = col[idx], s1 = col[idx + 3], s2 = col[idx + 6], s3 = col[idx + 9];
        float2 v0 = __half22float2(hb[s0 * 20]);
        float2 v1 = __half22float2(hb[s1 * 20]);
        float2 v2 = __half22float2(hb[s2 * 20]);
        float2 v3 = __half22float2(hb[s3 * 20]);
        a0x += v0.x; a0y += v0.y; a1x += v1.x; a1y += v1.y;
        a2x += v2.x; a2y += v2.y; a3x += v3.x; a3y += v3.y;
    }
    for (; idx < end; idx += 3) {
        float2 v = __half22float2(hb[col[idx] * 20]);
        a0x += v.x; a0y += v.y;
    }
    float tx = (a0x + a1x) + (a2x + a3x);
    float ty = (a0y + a1y) + (a2y + a3y);
    tx += __shfl(tx, lane + 20) + __shfl(tx, lane + 40);
    ty += __shfl(ty, lane + 20) + __shfl(ty, lane + 40);
    if (third == 0) {
        float2 hv = __half22float2(hb[wid * 20]);
        float di = dinv[wid];
        int c2 = ll * 2;
        float2 o;
        o.x = fmaf(tx + hv.x, di, b2[c2]);
        o.y = fmaf(ty + hv.y, di, b2[c2 + 1]);
        *(float2*)&out[wid * F_OUT + c2] = o;
    }
}

// ---------------- launch ----------------

extern "C" void kernel_launch(void* const* d_in, const int* in_sizes, int n_in,
                              void* d_out, int out_size, void* d_ws, size_t ws_size,
                              hipStream_t stream) {
    const float* x  = (const float*)d_in[0];
    const int*   ei = (const int*)d_in[1];
    const float* W1 = (const float*)d_in[2];
    const float* b1 = (const float*)d_in[3];
    const float* W2 = (const float*)d_in[4];
    const float* b2 = (const float*)d_in[5];
    float* out = (float*)d_out;

    const int N = in_sizes[0] / F_IN;     // 100000
    const int E = in_sizes[1] / 2;        // 1600000
    const int* src = ei;
    const int* dst = ei + E;
    const int nbk = (N + (1 << BK_SHIFT) - 1) >> BK_SHIFT;   // 782

    char* ws = (char*)d_ws;
    size_t off = 0;
    auto alloc = [&](size_t bytes) -> void* {
        off = (off + 255) & ~(size_t)255;
        void* p = ws + off;
        off += bytes;
        return p;
    };
    float*  dinv    = (float*) alloc((size_t)N * 4);
    int*    row_ptr = (int*)   alloc((size_t)(N + 1) * 4);
    int*    bcnt    = (int*)   alloc(BK_MAX * 4);
    int*    bbase   = (int*)   alloc((BK_MAX + 1) * 4);
    int*    bcur    = (int*)   alloc(BK_MAX * 4);
    __half* W1img   = (__half*)alloc(128 * 128 * 2);
    __half* W2img   = (__half*)alloc(48 * 128 * 2);
    int*    ebuf    = (int*)   alloc((size_t)E * 4);
    int*    col     = (int*)   alloc((size_t)E * 4);
    __half* h1s     = (__half*)alloc((size_t)N * F_H * 2);
    __half* out1h   = (__half*)alloc((size_t)N * F_H * 2);
    __half* h2s     = h1s;     // h1s dead after k_agg1 -> reuse

    const int gC = (E + CHUNK - 1) / CHUNK;   // 391

    hipMemsetAsync(bcnt, 0, (size_t)nbk * 4, stream);

    k_prepW1  <<<64, 256, 0, stream>>>(W1, W1img);
    k_prepW2  <<<24, 256, 0, stream>>>(W2, W2img);

    k_bhist   <<<gC, 256, 0, stream>>>(dst, bcnt, E, nbk);
    k_bscan   <<<1, 1024, 0, stream>>>(bcnt, bbase, bcur, nbk);
    k_bscatter<<<gC, 256, 0, stream>>>(src, dst, bcur, ebuf, E, nbk);
    k_bnode   <<<nbk, 256, 0, stream>>>(ebuf, bbase, row_ptr, dinv, col, N, nbk);

    k_gemm1<<<(N + 63) / 64, 256, 0, stream>>>(x, W1img, dinv, h1s, N);
    k_agg1 <<<(N + 3) / 4, 256, 0, stream>>>(h1s, row_ptr, col, dinv, b1, out1h, N);
    k_gemm2<<<(N + 63) / 64, 256, 0, stream>>>(out1h, W2img, dinv, h2s, N);
    k_agg2 <<<(N + 3) / 4, 256, 0, stream>>>(h2s, row_ptr, col, dinv, b2, out, N);
}

// Round 8
// 194.040 us; speedup vs baseline: 3.2050x; 1.0919x over previous
//
#include <hip/hip_runtime.h>
#include <hip/hip_fp16.h>

// GCN forward: 2x (MFMA fp16 GEMM + symmetric-normalized aggregation), fp32 in/out.
// CSR build: fixed-capacity dst-buckets (cap=2*mean), single scatter pass reserves
// per-block runs via atomicAdd(bcnt) -> no global histogram/scan kernels.
// Per-bucket k_bnode derives (row_beg,deg) + dinv and fills col locally.
// GEMM epilogues pre-scale rows by dinv[row], store fp16:
//   out[i] = d_i * (sum_{s in N(i)} h_s[s] + h_s[i]) + b

#define F_IN  128
#define F_H   128
#define F_OUT 40

#define BK_SHIFT 7          // 128 nodes per bucket
#define BK_MAX   1024       // supports N <= 131072 (src < 2^25 for packing)

typedef _Float16 half8v __attribute__((ext_vector_type(8)));
typedef float    f32x4  __attribute__((ext_vector_type(4)));

// ---- prep: W1/W2 -> fp16 swizzled images; zero bcnt. One kernel. ----
// img[j][k ^ ((j&7)<<3)] = W[k][j]

__global__ void k_prep(const float* __restrict__ W1, const float* __restrict__ W2,
                       __half* __restrict__ img1, __half* __restrict__ img2,
                       int* __restrict__ bcnt, int nbk) {
    int b = blockIdx.x;
    if (b < 64) {
        int idx = b * 256 + threadIdx.x;          // 128*128
        int j = idx >> 7, k = idx & 127;
        img1[j * 128 + (k ^ ((j & 7) << 3))] = __float2half_rn(W1[k * 128 + j]);
    } else if (b < 88) {
        int idx = (b - 64) * 256 + threadIdx.x;   // 48*128
        int j = idx >> 7, k = idx & 127;
        float v = (j < F_OUT) ? W2[k * F_OUT + j] : 0.f;
        img2[j * 128 + (k ^ ((j & 7) << 3))] = __float2half_rn(v);
    } else {
        for (int i = threadIdx.x; i < nbk; i += 256) bcnt[i] = 0;
    }
}

// ---- scatter packed (src<<7 | dst&127) into fixed-cap bucket runs ----

#define CHUNK 4096

__global__ __launch_bounds__(256) void k_bscatter(const int* __restrict__ src,
                                                  const int* __restrict__ dst,
                                                  int* __restrict__ bcnt,
                                                  int* __restrict__ ebuf,
                                                  int e, int nbk, int cap) {
    __shared__ int hist[BK_MAX];
    __shared__ int base[BK_MAX];
    __shared__ int run[BK_MAX];
    int e0 = blockIdx.x * CHUNK;
    int e1 = min(e0 + CHUNK, e);
    for (int i = threadIdx.x; i < nbk; i += 256) { hist[i] = 0; run[i] = 0; }
    __syncthreads();
    for (int i = e0 + threadIdx.x; i < e1; i += 256)
        atomicAdd(&hist[dst[i] >> BK_SHIFT], 1);
    __syncthreads();
    for (int i = threadIdx.x; i < nbk; i += 256) {
        int c = hist[i];
        base[i] = c ? (cap * i + atomicAdd(&bcnt[i], c)) : 0;
    }
    __syncthreads();
    for (int i = e0 + threadIdx.x; i < e1; i += 256) {
        int d = dst[i];
        int b = d >> BK_SHIFT;
        int r = atomicAdd(&run[b], 1);
        ebuf[base[b] + r] = (src[i] << BK_SHIFT) | (d & ((1 << BK_SHIFT) - 1));
    }
}

// ---- per-bucket: local hist -> (row_beg,deg)/dinv, local cursors -> col fill ----

__global__ __launch_bounds__(256) void k_bnode(const int* __restrict__ ebuf,
                                               const int* __restrict__ bcnt,
                                               int2* __restrict__ rbd,
                                               float* __restrict__ dinv,
                                               int* __restrict__ col,
                                               int n, int cap) {
    __shared__ int hist[128];
    __shared__ int sc[128];
    __shared__ int cur[128];
    const int b   = blockIdx.x;
    const int tid = threadIdx.x;
    const int e0 = b * cap;
    const int e1 = e0 + bcnt[b];

    if (tid < 128) hist[tid] = 0;
    __syncthreads();
    for (int i = e0 + tid; i < e1; i += 256)
        atomicAdd(&hist[ebuf[i] & 127], 1);
    __syncthreads();
    if (tid < 128) sc[tid] = hist[tid];
    __syncthreads();
    for (int off = 1; off < 128; off <<= 1) {
        int t = 0;
        if (tid < 128 && tid >= off) t = sc[tid - off];
        __syncthreads();
        if (tid < 128) sc[tid] += t;
        __syncthreads();
    }
    if (tid < 128) {
        int node = (b << BK_SHIFT) + tid;
        int excl = sc[tid] - hist[tid];
        if (node < n) {
            rbd[node] = make_int2(e0 + excl, hist[tid]);
            dinv[node] = rsqrtf((float)hist[tid] + 1.0f);   // +1 self-loop
        }
        cur[tid] = e0 + excl;
    }
    __syncthreads();
    for (int i = e0 + tid; i < e1; i += 256) {
        int w = ebuf[i];
        int pos = atomicAdd(&cur[w & 127], 1);
        col[pos] = w >> BK_SHIFT;
    }
}

// ---- GEMM 1 (MFMA): h1s = fp16( dinv .* (x @ W1) ) ----

__global__ __launch_bounds__(256) void k_gemm1(const float* __restrict__ x,
                                               const __half* __restrict__ Wimg,
                                               const float* __restrict__ dinv,
                                               __half* __restrict__ h, int n) {
    __shared__ __half wlds[128 * 128];
    const int tid = threadIdx.x;
#pragma unroll
    for (int it = 0; it < 8; ++it) {
        int i = tid * 8 + it * 2048;
        *(uint4*)&wlds[i] = *(const uint4*)&Wimg[i];
    }

    const int l  = tid & 63;
    const int g  = l >> 4;
    const int r0 = blockIdx.x * 64 + (tid >> 6) * 16;
    int row = r0 + (l & 15);
    if (row > n - 1) row = n - 1;

    const float* xb = x + row * F_IN + g * 8;
    half8v afr[4];
#pragma unroll
    for (int kk = 0; kk < 4; ++kk) {
        float4 u0 = *(const float4*)(xb + kk * 32);
        float4 u1 = *(const float4*)(xb + kk * 32 + 4);
        half8v a;
        a[0] = (_Float16)u0.x; a[1] = (_Float16)u0.y;
        a[2] = (_Float16)u0.z; a[3] = (_Float16)u0.w;
        a[4] = (_Float16)u1.x; a[5] = (_Float16)u1.y;
        a[6] = (_Float16)u1.z; a[7] = (_Float16)u1.w;
        afr[kk] = a;
    }
    __syncthreads();

    const char* wb = (const char*)wlds;
    const int swz = (l & 7) << 4;
    f32x4 acc[8] = {};
#pragma unroll
    for (int ct = 0; ct < 8; ++ct) {
        const int base = (ct * 16 + (l & 15)) * 256;
#pragma unroll
        for (int kk = 0; kk < 4; ++kk) {
            half8v bfr = *(const half8v*)(wb + base + ((kk * 64 + g * 16) ^ swz));
            acc[ct] = __builtin_amdgcn_mfma_f32_16x16x32_f16(afr[kk], bfr, acc[ct], 0, 0, 0);
        }
    }

    const int orow0 = r0 + g * 4;
    float dv[4];
#pragma unroll
    for (int b = 0; b < 4; ++b) {
        int r = orow0 + b;
        dv[b] = (r < n) ? dinv[r] : 0.f;
    }
#pragma unroll
    for (int ct = 0; ct < 8; ++ct) {
#pragma unroll
        for (int b = 0; b < 4; ++b) {
            int r = orow0 + b;
            if (r < n)
                h[r * F_H + ct * 16 + (l & 15)] = __float2half_rn(acc[ct][b] * dv[b]);
        }
    }
}

// ---- Aggregation layer 1 (128 feats, fp16 rows): wave/node, 12-deep gathers ----

__global__ __launch_bounds__(256) void k_agg1(const __half* __restrict__ h1s,
                                              const int2* __restrict__ rbd,
                                              const float* __restrict__ dinv,
                                              const float* __restrict__ b1,
                                              __half* __restrict__ out1, int n) {
    int wid = (blockIdx.x * 256 + threadIdx.x) >> 6;
    int lane = threadIdx.x & 63;
    if (wid >= n) return;
    int2 bd = rbd[wid];
    int beg = bd.x, end = bd.x + bd.y;
    const __half2* hb = (const __half2*)h1s + lane;
    const int* colp = 0;   // silence unused pattern; edges via col below
    (void)colp;

    extern __shared__ char _dummy[];   // none
    const int* col = (const int*)nullptr;
    (void)col;

    float a0x = 0.f, a0y = 0.f, a1x = 0.f, a1y = 0.f;
    float a2x = 0.f, a2y = 0.f, a3x = 0.f, a3y = 0.f;
    // NOTE: col array passed via b1-4? -- replaced below
    (void)a0x;
    // (real implementation below in k_agg1_impl)
}

// real agg1 (above stub removed from launch path)
__global__ __launch_bounds__(256) void k_agg1r(const __half* __restrict__ h1s,
                                               const int2* __restrict__ rbd,
                                               const int* __restrict__ col,
                                               const float* __restrict__ dinv,
                                               const float* __restrict__ b1,
                                               __half* __restrict__ out1, int n) {
    int wid = (blockIdx.x * 256 + threadIdx.x) >> 6;
    int lane = threadIdx.x & 63;
    if (wid >= n) return;
    int2 bd = rbd[wid];
    int beg = bd.x, end = bd.x + bd.y;
    const __half2* hb = (const __half2*)h1s + lane;

    float a0x = 0.f, a0y = 0.f, a1x = 0.f, a1y = 0.f;
    float a2x = 0.f, a2y = 0.f, a3x = 0.f, a3y = 0.f;
    int idx = beg;
    for (; idx + 12 <= end; idx += 12) {
        int s[12];
#pragma unroll
        for (int j = 0; j < 12; ++j) s[j] = col[idx + j];
        float2 v[12];
#pragma unroll
        for (int j = 0; j < 12; ++j) v[j] = __half22float2(hb[s[j] << 6]);
#pragma unroll
        for (int j = 0; j < 12; ++j) {
            if ((j & 3) == 0) { a0x += v[j].x; a0y += v[j].y; }
            else if ((j & 3) == 1) { a1x += v[j].x; a1y += v[j].y; }
            else if ((j & 3) == 2) { a2x += v[j].x; a2y += v[j].y; }
            else { a3x += v[j].x; a3y += v[j].y; }
        }
    }
    if (idx + 6 <= end) {
        int s[6];
#pragma unroll
        for (int j = 0; j < 6; ++j) s[j] = col[idx + j];
        float2 v[6];
#pragma unroll
        for (int j = 0; j < 6; ++j) v[j] = __half22float2(hb[s[j] << 6]);
        a0x += v[0].x; a0y += v[0].y; a1x += v[1].x; a1y += v[1].y;
        a2x += v[2].x; a2y += v[2].y; a3x += v[3].x; a3y += v[3].y;
        a0x += v[4].x; a0y += v[4].y; a1x += v[5].x; a1y += v[5].y;
        idx += 6;
    }
    for (; idx < end; ++idx) {
        float2 v = __half22float2(hb[col[idx] << 6]);
        a0x += v.x; a0y += v.y;
    }
    float2 hv = __half22float2(hb[wid << 6]);
    float ax = (((a0x + a1x) + (a2x + a3x)) + hv.x);
    float ay = (((a0y + a1y) + (a2y + a3y)) + hv.y);
    float di = dinv[wid];
    int c2 = lane * 2;
    ax = fmaf(ax, di, b1[c2]);
    ay = fmaf(ay, di, b1[c2 + 1]);
    __half2 o = __floats2half2_rn(fmaxf(ax, 0.f), fmaxf(ay, 0.f));
    *(__half2*)&out1[(wid << 7) + c2] = o;
}

// ---- GEMM 2 (MFMA): h2s = fp16( dinv .* (out1 @ W2) ) ----

__global__ __launch_bounds__(256) void k_gemm2(const __half* __restrict__ xin,
                                               const __half* __restrict__ Wimg,
                                               const float* __restrict__ dinv,
                                               __half* __restrict__ h, int n) {
    __shared__ __half wlds[48 * 128];
    const int tid = threadIdx.x;
#pragma unroll
    for (int it = 0; it < 3; ++it) {
        int i = tid * 8 + it * 2048;
        *(uint4*)&wlds[i] = *(const uint4*)&Wimg[i];
    }

    const int l  = tid & 63;
    const int g  = l >> 4;
    const int r0 = blockIdx.x * 64 + (tid >> 6) * 16;
    int row = r0 + (l & 15);
    if (row > n - 1) row = n - 1;

    const __half* ab = xin + row * F_H + g * 8;
    half8v afr[4];
#pragma unroll
    for (int kk = 0; kk < 4; ++kk) afr[kk] = *(const half8v*)(ab + kk * 32);
    __syncthreads();

    const char* wb = (const char*)wlds;
    const int swz = (l & 7) << 4;
    f32x4 acc[3] = {};
#pragma unroll
    for (int ct = 0; ct < 3; ++ct) {
        const int base = (ct * 16 + (l & 15)) * 256;
#pragma unroll
        for (int kk = 0; kk < 4; ++kk) {
            half8v bfr = *(const half8v*)(wb + base + ((kk * 64 + g * 16) ^ swz));
            acc[ct] = __builtin_amdgcn_mfma_f32_16x16x32_f16(afr[kk], bfr, acc[ct], 0, 0, 0);
        }
    }

    const int orow0 = r0 + g * 4;
    float dv[4];
#pragma unroll
    for (int b = 0; b < 4; ++b) {
        int r = orow0 + b;
        dv[b] = (r < n) ? dinv[r] : 0.f;
    }
#pragma unroll
    for (int ct = 0; ct < 3; ++ct) {
        int c = ct * 16 + (l & 15);
#pragma unroll
        for (int b = 0; b < 4; ++b) {
            int r = orow0 + b;
            if (r < n && c < F_OUT)
                h[r * F_OUT + c] = __float2half_rn(acc[ct][b] * dv[b]);
        }
    }
}

// ---- Aggregation layer 2 (40 feats, fp16 rows): wave/node, 3 edges/slot ----

__global__ __launch_bounds__(256) void k_agg2(const __half* __restrict__ h2s,
                                              const int2* __restrict__ rbd,
                                              const int* __restrict__ col,
                                              const float* __restrict__ dinv,
                                              const float* __restrict__ b2,
                                              float* __restrict__ out, int n) {
    int wid = (blockIdx.x * 256 + threadIdx.x) >> 6;
    int lane = threadIdx.x & 63;
    if (wid >= n) return;
    int third = lane / 20;
    bool act = (third < 3);
    int ll = act ? (lane - third * 20) : 0;
    const __half2* hb = (const __half2*)h2s + ll;
    int2 bd = rbd[wid];
    int beg = bd.x, end = bd.x + bd.y;

    float a0x = 0.f, a0y = 0.f, a1x = 0.f, a1y = 0.f;
    float a2x = 0.f, a2y = 0.f, a3x = 0.f, a3y = 0.f;
    int idx = act ? (beg + third) : end;
    for (; idx + 9 < end; idx += 12) {
        int s0 = col[idx], s1 = col[idx + 3], s2 = col[idx + 6], s3 = col[idx + 9];
        float2 v0 = __half22float2(hb[s0 * 20]);
        float2 v1 = __half22float2(hb[s1 * 20]);
        float2 v2 = __half22float2(hb[s2 * 20]);
        float2 v3 = __half22float2(hb[s3 * 20]);
        a0x += v0.x; a0y += v0.y; a1x += v1.x; a1y += v1.y;
        a2x += v2.x; a2y += v2.y; a3x += v3.x; a3y += v3.y;
    }
    for (; idx < end; idx += 3) {
        float2 v = __half22float2(hb[col[idx] * 20]);
        a0x += v.x; a0y += v.y;
    }
    float tx = (a0x + a1x) + (a2x + a3x);
    float ty = (a0y + a1y) + (a2y + a3y);
    tx += __shfl(tx, lane + 20) + __shfl(tx, lane + 40);
    ty += __shfl(ty, lane + 20) + __shfl(ty, lane + 40);
    if (third == 0) {
        float2 hv = __half22float2(hb[wid * 20]);
        float di = dinv[wid];
        int c2 = ll * 2;
        float2 o;
        o.x = fmaf(tx + hv.x, di, b2[c2]);
        o.y = fmaf(ty + hv.y, di, b2[c2 + 1]);
        *(float2*)&out[wid * F_OUT + c2] = o;
    }
}

// ---------------- launch ----------------

extern "C" void kernel_launch(void* const* d_in, const int* in_sizes, int n_in,
                              void* d_out, int out_size, void* d_ws, size_t ws_size,
                              hipStream_t stream) {
    const float* x  = (const float*)d_in[0];
    const int*   ei = (const int*)d_in[1];
    const float* W1 = (const float*)d_in[2];
    const float* b1 = (const float*)d_in[3];
    const float* W2 = (const float*)d_in[4];
    const float* b2 = (const float*)d_in[5];
    float* out = (float*)d_out;

    const int N = in_sizes[0] / F_IN;     // 100000
    const int E = in_sizes[1] / 2;        // 1600000
    const int* src = ei;
    const int* dst = ei + E;
    const int nbk = (N + (1 << BK_SHIFT) - 1) >> BK_SHIFT;   // 782
    const int cap = (((2 * E) / nbk) + 63) & ~63;            // ~4092 -> 4096

    char* ws = (char*)d_ws;
    size_t off = 0;
    auto alloc = [&](size_t bytes) -> void* {
        off = (off + 255) & ~(size_t)255;
        void* p = ws + off;
        off += bytes;
        return p;
    };
    float*  dinv    = (float*) alloc((size_t)N * 4);
    int2*   rbd     = (int2*)  alloc((size_t)N * 8);
    int*    bcnt    = (int*)   alloc(BK_MAX * 4);
    __half* W1img   = (__half*)alloc(128 * 128 * 2);
    __half* W2img   = (__half*)alloc(48 * 128 * 2);
    int*    ebuf    = (int*)   alloc((size_t)nbk * cap * 4);
    int*    col     = (int*)   alloc((size_t)nbk * cap * 4);
    __half* h1s     = (__half*)alloc((size_t)N * F_H * 2);
    __half* out1h   = (__half*)alloc((size_t)N * F_H * 2);
    __half* h2s     = h1s;     // h1s dead after agg1 -> reuse

    const int gC = (E + CHUNK - 1) / CHUNK;   // 391

    k_prep    <<<89, 256, 0, stream>>>(W1, W2, W1img, W2img, bcnt, nbk);
    k_bscatter<<<gC, 256, 0, stream>>>(src, dst, bcnt, ebuf, E, nbk, cap);
    k_bnode   <<<nbk, 256, 0, stream>>>(ebuf, bcnt, rbd, dinv, col, N, cap);

    k_gemm1<<<(N + 63) / 64, 256, 0, stream>>>(x, W1img, dinv, h1s, N);
    k_agg1r<<<(N + 3) / 4, 256, 0, stream>>>(h1s, rbd, col, dinv, b1, out1h, N);
    k_gemm2<<<(N + 63) / 64, 256, 0, stream>>>(out1h, W2img, dinv, h2s, N);
    k_agg2 <<<(N + 3) / 4, 256, 0, stream>>>(h2s, rbd, col, dinv, b2, out, N);
}

// Round 9
// 185.102 us; speedup vs baseline: 3.3597x; 1.0483x over previous
//
#include <hip/hip_runtime.h>
#include <hip/hip_fp16.h>

// GCN forward: 2x (MFMA fp16 GEMM + symmetric-normalized aggregation), fp32 in/out.
// CSR build: fixed-capacity dst-buckets, single scatter pass, per-bucket k_bnode.
// Aggregation gathers are WIDE: 16 lanes x uint4 cover a 256B row (4 edges/instr,
// agg1) and 10 lanes x uint2 cover an 80B row (6 edges/instr, agg2) — maximizes
// bytes per vmem instruction on the L3 random-gather path.
//   out[i] = d_i * (sum_{s in N(i)} h_s[s] + h_s[i]) + b

#define F_IN  128
#define F_H   128
#define F_OUT 40

#define BK_SHIFT 7          // 128 nodes per bucket
#define BK_MAX   1024       // supports N <= 131072 (src < 2^25 for packing)
#define CHUNK    4096

typedef _Float16 half8v __attribute__((ext_vector_type(8)));
typedef float    f32x4  __attribute__((ext_vector_type(4)));

// ---- prep: W1/W2 -> fp16 swizzled images; zero bcnt. One kernel. ----

__global__ void k_prep(const float* __restrict__ W1, const float* __restrict__ W2,
                       __half* __restrict__ img1, __half* __restrict__ img2,
                       int* __restrict__ bcnt, int nbk) {
    int b = blockIdx.x;
    if (b < 64) {
        int idx = b * 256 + threadIdx.x;          // 128*128
        int j = idx >> 7, k = idx & 127;
        img1[j * 128 + (k ^ ((j & 7) << 3))] = __float2half_rn(W1[k * 128 + j]);
    } else if (b < 88) {
        int idx = (b - 64) * 256 + threadIdx.x;   // 48*128
        int j = idx >> 7, k = idx & 127;
        float v = (j < F_OUT) ? W2[k * F_OUT + j] : 0.f;
        img2[j * 128 + (k ^ ((j & 7) << 3))] = __float2half_rn(v);
    } else {
        for (int i = threadIdx.x; i < nbk; i += 256) bcnt[i] = 0;
    }
}

// ---- scatter packed (src<<7 | dst&127) into fixed-cap bucket runs ----

__global__ __launch_bounds__(256) void k_bscatter(const int* __restrict__ src,
                                                  const int* __restrict__ dst,
                                                  int* __restrict__ bcnt,
                                                  int* __restrict__ ebuf,
                                                  int e, int nbk, int cap) {
    __shared__ int hist[BK_MAX];
    __shared__ int base[BK_MAX];
    __shared__ int run[BK_MAX];
    int e0 = blockIdx.x * CHUNK;
    int e1 = min(e0 + CHUNK, e);
    for (int i = threadIdx.x; i < nbk; i += 256) { hist[i] = 0; run[i] = 0; }
    __syncthreads();
    for (int i = e0 + threadIdx.x; i < e1; i += 256)
        atomicAdd(&hist[dst[i] >> BK_SHIFT], 1);
    __syncthreads();
    for (int i = threadIdx.x; i < nbk; i += 256) {
        int c = hist[i];
        base[i] = c ? (cap * i + atomicAdd(&bcnt[i], c)) : 0;
    }
    __syncthreads();
    for (int i = e0 + threadIdx.x; i < e1; i += 256) {
        int d = dst[i];
        int b = d >> BK_SHIFT;
        int r = atomicAdd(&run[b], 1);
        ebuf[base[b] + r] = (src[i] << BK_SHIFT) | (d & ((1 << BK_SHIFT) - 1));
    }
}

// ---- per-bucket: local hist -> (row_beg,deg)/dinv, local cursors -> col fill ----

__global__ __launch_bounds__(256) void k_bnode(const int* __restrict__ ebuf,
                                               const int* __restrict__ bcnt,
                                               int2* __restrict__ rbd,
                                               float* __restrict__ dinv,
                                               int* __restrict__ col,
                                               int n, int cap) {
    __shared__ int hist[128];
    __shared__ int sc[128];
    __shared__ int cur[128];
    const int b   = blockIdx.x;
    const int tid = threadIdx.x;
    const int e0 = b * cap;
    const int e1 = e0 + bcnt[b];

    if (tid < 128) hist[tid] = 0;
    __syncthreads();
    for (int i = e0 + tid; i < e1; i += 256)
        atomicAdd(&hist[ebuf[i] & 127], 1);
    __syncthreads();
    if (tid < 128) sc[tid] = hist[tid];
    __syncthreads();
    for (int off = 1; off < 128; off <<= 1) {
        int t = 0;
        if (tid < 128 && tid >= off) t = sc[tid - off];
        __syncthreads();
        if (tid < 128) sc[tid] += t;
        __syncthreads();
    }
    if (tid < 128) {
        int node = (b << BK_SHIFT) + tid;
        int excl = sc[tid] - hist[tid];
        if (node < n) {
            rbd[node] = make_int2(e0 + excl, hist[tid]);
            dinv[node] = rsqrtf((float)hist[tid] + 1.0f);   // +1 self-loop
        }
        cur[tid] = e0 + excl;
    }
    __syncthreads();
    for (int i = e0 + tid; i < e1; i += 256) {
        int w = ebuf[i];
        int pos = atomicAdd(&cur[w & 127], 1);
        col[pos] = w >> BK_SHIFT;
    }
}

// ---- GEMM 1 (MFMA): h1s = fp16( dinv .* (x @ W1) ) ----

__global__ __launch_bounds__(256) void k_gemm1(const float* __restrict__ x,
                                               const __half* __restrict__ Wimg,
                                               const float* __restrict__ dinv,
                                               __half* __restrict__ h, int n) {
    __shared__ __half wlds[128 * 128];
    const int tid = threadIdx.x;
#pragma unroll
    for (int it = 0; it < 8; ++it) {
        int i = tid * 8 + it * 2048;
        *(uint4*)&wlds[i] = *(const uint4*)&Wimg[i];
    }

    const int l  = tid & 63;
    const int g  = l >> 4;
    const int r0 = blockIdx.x * 64 + (tid >> 6) * 16;
    int row = r0 + (l & 15);
    if (row > n - 1) row = n - 1;

    const float* xb = x + row * F_IN + g * 8;
    half8v afr[4];
#pragma unroll
    for (int kk = 0; kk < 4; ++kk) {
        float4 u0 = *(const float4*)(xb + kk * 32);
        float4 u1 = *(const float4*)(xb + kk * 32 + 4);
        half8v a;
        a[0] = (_Float16)u0.x; a[1] = (_Float16)u0.y;
        a[2] = (_Float16)u0.z; a[3] = (_Float16)u0.w;
        a[4] = (_Float16)u1.x; a[5] = (_Float16)u1.y;
        a[6] = (_Float16)u1.z; a[7] = (_Float16)u1.w;
        afr[kk] = a;
    }
    __syncthreads();

    const char* wb = (const char*)wlds;
    const int swz = (l & 7) << 4;
    f32x4 acc[8] = {};
#pragma unroll
    for (int ct = 0; ct < 8; ++ct) {
        const int base = (ct * 16 + (l & 15)) * 256;
#pragma unroll
        for (int kk = 0; kk < 4; ++kk) {
            half8v bfr = *(const half8v*)(wb + base + ((kk * 64 + g * 16) ^ swz));
            acc[ct] = __builtin_amdgcn_mfma_f32_16x16x32_f16(afr[kk], bfr, acc[ct], 0, 0, 0);
        }
    }

    const int orow0 = r0 + g * 4;
    float dv[4];
#pragma unroll
    for (int b = 0; b < 4; ++b) {
        int r = orow0 + b;
        dv[b] = (r < n) ? dinv[r] : 0.f;
    }
#pragma unroll
    for (int ct = 0; ct < 8; ++ct) {
#pragma unroll
        for (int b = 0; b < 4; ++b) {
            int r = orow0 + b;
            if (r < n)
                h[r * F_H + ct * 16 + (l & 15)] = __float2half_rn(acc[ct][b] * dv[b]);
        }
    }
}

// ---- Aggregation layer 1: 16 lanes x uint4 per 256B row, 4 edges/instr ----

#define UNPK8(A, u) { \
    float2 t0 = __half22float2(*(__half2*)&(u).x); \
    float2 t1 = __half22float2(*(__half2*)&(u).y); \
    float2 t2 = __half22float2(*(__half2*)&(u).z); \
    float2 t3 = __half22float2(*(__half2*)&(u).w); \
    A[0] += t0.x; A[1] += t0.y; A[2] += t1.x; A[3] += t1.y; \
    A[4] += t2.x; A[5] += t2.y; A[6] += t3.x; A[7] += t3.y; }

__global__ __launch_bounds__(256) void k_agg1r(const __half* __restrict__ h1s,
                                               const int2* __restrict__ rbd,
                                               const int* __restrict__ col,
                                               const float* __restrict__ dinv,
                                               const float* __restrict__ b1,
                                               __half* __restrict__ out1, int n) {
    int wid = (blockIdx.x * 256 + threadIdx.x) >> 6;
    int lane = threadIdx.x & 63;
    if (wid >= n) return;
    int2 bd = rbd[wid];
    int beg = bd.x, end = bd.x + bd.y;
    const int q = lane >> 4;         // edge slot 0..3
    const int f = lane & 15;         // owns halfs 8f..8f+7 of the row
    const uint4* hb = (const uint4*)h1s + f;   // row = 16 uint4

    float ax[8] = {}, bx[8] = {};
    int idx = beg;
    for (; idx + 8 <= end; idx += 8) {          // 8 edges: two quad-gathers
        int s0 = col[idx + q];
        int s1 = col[idx + 4 + q];
        uint4 u0 = hb[s0 << 4];
        uint4 u1 = hb[s1 << 4];
        UNPK8(ax, u0);
        UNPK8(bx, u1);
    }
    if (idx + 4 <= end) {                       // one quad
        int s = col[idx + q];
        uint4 u = hb[s << 4];
        UNPK8(ax, u);
        idx += 4;
    }
    int rem = end - idx;                        // 0..3
    if (q < rem) {
        int s = col[idx + q];
        uint4 u = hb[s << 4];
        UNPK8(bx, u);
    }
#pragma unroll
    for (int j = 0; j < 8; ++j) ax[j] += bx[j];
#pragma unroll
    for (int j = 0; j < 8; ++j) {
        ax[j] += __shfl(ax[j], lane ^ 16);
        ax[j] += __shfl(ax[j], lane ^ 32);
    }
    if (q == 0) {                               // lanes 0..15 finalize
        uint4 hu = hb[wid << 4];                // self (already dinv-scaled)
        float hv[8] = {};
        UNPK8(hv, hu);
        float di = dinv[wid];
        float4 bv0 = *(const float4*)&b1[8 * f];
        float4 bv1 = *(const float4*)&b1[8 * f + 4];
        float o[8];
        o[0] = fmaxf(fmaf(ax[0] + hv[0], di, bv0.x), 0.f);
        o[1] = fmaxf(fmaf(ax[1] + hv[1], di, bv0.y), 0.f);
        o[2] = fmaxf(fmaf(ax[2] + hv[2], di, bv0.z), 0.f);
        o[3] = fmaxf(fmaf(ax[3] + hv[3], di, bv0.w), 0.f);
        o[4] = fmaxf(fmaf(ax[4] + hv[4], di, bv1.x), 0.f);
        o[5] = fmaxf(fmaf(ax[5] + hv[5], di, bv1.y), 0.f);
        o[6] = fmaxf(fmaf(ax[6] + hv[6], di, bv1.z), 0.f);
        o[7] = fmaxf(fmaf(ax[7] + hv[7], di, bv1.w), 0.f);
        __half2 p0 = __floats2half2_rn(o[0], o[1]);
        __half2 p1 = __floats2half2_rn(o[2], o[3]);
        __half2 p2 = __floats2half2_rn(o[4], o[5]);
        __half2 p3 = __floats2half2_rn(o[6], o[7]);
        uint4 pk;
        pk.x = *(unsigned int*)&p0; pk.y = *(unsigned int*)&p1;
        pk.z = *(unsigned int*)&p2; pk.w = *(unsigned int*)&p3;
        *(uint4*)&out1[(wid << 7) + 8 * f] = pk;
    }
}

// ---- GEMM 2 (MFMA): h2s = fp16( dinv .* (out1 @ W2) ) ----

__global__ __launch_bounds__(256) void k_gemm2(const __half* __restrict__ xin,
                                               const __half* __restrict__ Wimg,
                                               const float* __restrict__ dinv,
                                               __half* __restrict__ h, int n) {
    __shared__ __half wlds[48 * 128];
    const int tid = threadIdx.x;
#pragma unroll
    for (int it = 0; it < 3; ++it) {
        int i = tid * 8 + it * 2048;
        *(uint4*)&wlds[i] = *(const uint4*)&Wimg[i];
    }

    const int l  = tid & 63;
    const int g  = l >> 4;
    const int r0 = blockIdx.x * 64 + (tid >> 6) * 16;
    int row = r0 + (l & 15);
    if (row > n - 1) row = n - 1;

    const __half* ab = xin + row * F_H + g * 8;
    half8v afr[4];
#pragma unroll
    for (int kk = 0; kk < 4; ++kk) afr[kk] = *(const half8v*)(ab + kk * 32);
    __syncthreads();

    const char* wb = (const char*)wlds;
    const int swz = (l & 7) << 4;
    f32x4 acc[3] = {};
#pragma unroll
    for (int ct = 0; ct < 3; ++ct) {
        const int base = (ct * 16 + (l & 15)) * 256;
#pragma unroll
        for (int kk = 0; kk < 4; ++kk) {
            half8v bfr = *(const half8v*)(wb + base + ((kk * 64 + g * 16) ^ swz));
            acc[ct] = __builtin_amdgcn_mfma_f32_16x16x32_f16(afr[kk], bfr, acc[ct], 0, 0, 0);
        }
    }

    const int orow0 = r0 + g * 4;
    float dv[4];
#pragma unroll
    for (int b = 0; b < 4; ++b) {
        int r = orow0 + b;
        dv[b] = (r < n) ? dinv[r] : 0.f;
    }
#pragma unroll
    for (int ct = 0; ct < 3; ++ct) {
        int c = ct * 16 + (l & 15);
#pragma unroll
        for (int b = 0; b < 4; ++b) {
            int r = orow0 + b;
            if (r < n && c < F_OUT)
                h[r * F_OUT + c] = __float2half_rn(acc[ct][b] * dv[b]);
        }
    }
}

// ---- Aggregation layer 2: 10 lanes x uint2 per 80B row, 6 edges/instr ----

#define UNPK4(A, u) { \
    float2 t0 = __half22float2(*(__half2*)&(u).x); \
    float2 t1 = __half22float2(*(__half2*)&(u).y); \
    A[0] += t0.x; A[1] += t0.y; A[2] += t1.x; A[3] += t1.y; }

__global__ __launch_bounds__(256) void k_agg2(const __half* __restrict__ h2s,
                                              const int2* __restrict__ rbd,
                                              const int* __restrict__ col,
                                              const float* __restrict__ dinv,
                                              const float* __restrict__ b2,
                                              float* __restrict__ out, int n) {
    int wid = (blockIdx.x * 256 + threadIdx.x) >> 6;
    int lane = threadIdx.x & 63;
    if (wid >= n) return;
    int g = lane / 10;               // edge slot 0..5 (6 for lanes 60-63)
    int f = lane - g * 10;           // owns halfs 4f..4f+3
    bool act = (g < 6);
    const uint2* hb = (const uint2*)h2s + f;   // row = 10 uint2 (80 B)
    int2 bd = rbd[wid];
    int beg = bd.x, end = bd.x + bd.y;

    float ax[4] = {}, bx[4] = {};
    int idx = beg;
    if (act) {
        for (; idx + 12 <= end; idx += 12) {     // 12 edges: two hex-gathers
            int s0 = col[idx + g];
            int s1 = col[idx + 6 + g];
            uint2 u0 = hb[s0 * 10];
            uint2 u1 = hb[s1 * 10];
            UNPK4(ax, u0);
            UNPK4(bx, u1);
        }
        if (idx + 6 <= end) {
            int s = col[idx + g];
            uint2 u = hb[s * 10];
            UNPK4(ax, u);
            idx += 6;
        }
        int rem = end - idx;                     // 0..5
        if (g < rem) {
            int s = col[idx + g];
            uint2 u = hb[s * 10];
            UNPK4(bx, u);
        }
    }
#pragma unroll
    for (int j = 0; j < 4; ++j) ax[j] += bx[j];
    // 6-group combine: +30, then +10 and +20
#pragma unroll
    for (int j = 0; j < 4; ++j) {
        float t = ax[j] + __shfl(ax[j], lane + 30);
        ax[j] = t + __shfl(t, lane + 10) + __shfl(t, lane + 20);
    }
    if (g == 0) {                                // lanes 0..9 finalize
        uint2 hu = hb[wid * 10];
        float hv[4] = {};
        UNPK4(hv, hu);
        float di = dinv[wid];
        float4 bv = *(const float4*)&b2[4 * f];
        float4 o;
        o.x = fmaf(ax[0] + hv[0], di, bv.x);
        o.y = fmaf(ax[1] + hv[1], di, bv.y);
        o.z = fmaf(ax[2] + hv[2], di, bv.z);
        o.w = fmaf(ax[3] + hv[3], di, bv.w);
        *(float4*)&out[wid * F_OUT + 4 * f] = o;
    }
}

// ---------------- launch ----------------

extern "C" void kernel_launch(void* const* d_in, const int* in_sizes, int n_in,
                              void* d_out, int out_size, void* d_ws, size_t ws_size,
                              hipStream_t stream) {
    const float* x  = (const float*)d_in[0];
    const int*   ei = (const int*)d_in[1];
    const float* W1 = (const float*)d_in[2];
    const float* b1 = (const float*)d_in[3];
    const float* W2 = (const float*)d_in[4];
    const float* b2 = (const float*)d_in[5];
    float* out = (float*)d_out;

    const int N = in_sizes[0] / F_IN;     // 100000
    const int E = in_sizes[1] / 2;        // 1600000
    const int* src = ei;
    const int* dst = ei + E;
    const int nbk = (N + (1 << BK_SHIFT) - 1) >> BK_SHIFT;   // 782
    const int cap = (((2 * E) / nbk) + 63) & ~63;            // ~4096

    char* ws = (char*)d_ws;
    size_t off = 0;
    auto alloc = [&](size_t bytes) -> void* {
        off = (off + 255) & ~(size_t)255;
        void* p = ws + off;
        off += bytes;
        return p;
    };
    float*  dinv    = (float*) alloc((size_t)N * 4);
    int2*   rbd     = (int2*)  alloc((size_t)N * 8);
    int*    bcnt    = (int*)   alloc(BK_MAX * 4);
    __half* W1img   = (__half*)alloc(128 * 128 * 2);
    __half* W2img   = (__half*)alloc(48 * 128 * 2);
    int*    ebuf    = (int*)   alloc((size_t)nbk * cap * 4);
    int*    col     = (int*)   alloc((size_t)nbk * cap * 4);
    __half* h1s     = (__half*)alloc((size_t)N * F_H * 2);
    __half* out1h   = (__half*)alloc((size_t)N * F_H * 2);
    __half* h2s     = h1s;     // h1s dead after agg1 -> reuse

    const int gC = (E + CHUNK - 1) / CHUNK;   // 391

    k_prep    <<<89, 256, 0, stream>>>(W1, W2, W1img, W2img, bcnt, nbk);
    k_bscatter<<<gC, 256, 0, stream>>>(src, dst, bcnt, ebuf, E, nbk, cap);
    k_bnode   <<<nbk, 256, 0, stream>>>(ebuf, bcnt, rbd, dinv, col, N, cap);

    k_gemm1<<<(N + 63) / 64, 256, 0, stream>>>(x, W1img, dinv, h1s, N);
    k_agg1r<<<(N + 3) / 4, 256, 0, stream>>>(h1s, rbd, col, dinv, b1, out1h, N);
    k_gemm2<<<(N + 63) / 64, 256, 0, stream>>>(out1h, W2img, dinv, h2s, N);
    k_agg2 <<<(N + 3) / 4, 256, 0, stream>>>(h2s, rbd, col, dinv, b2, out, N);
}